// Round 4
// baseline (904.791 us; speedup 1.0000x reference)
//
#include <hip/hip_runtime.h>
#include <cmath>
#include <cstdint>

#define BB 16
#define NN_ 1024
#define DD 256

constexpr float INV_T = 1.0f / 0.07f;

typedef __attribute__((ext_vector_type(8))) short bf16x8;
typedef __attribute__((ext_vector_type(4))) float f32x4;

static __device__ __forceinline__ float b2f(ushort u) {
  union { uint i; float f; } c; c.i = ((uint)u) << 16; return c.f;
}
static __device__ __forceinline__ ushort f2b(float f) {
  union { float f; uint i; } c; c.f = f;
  uint r = c.i + 0x7fffu + ((c.i >> 16) & 1u);
  return (ushort)(r >> 16);
}

// ---------------- row normalize: z(f32) -> zn(bf16), both halves in one launch ----------------
__global__ __launch_bounds__(256) void k_norm(const float* __restrict__ z1, const float* __restrict__ z2,
                                              ushort* __restrict__ znAll) {
  const int row = blockIdx.x;  // 0 .. 2*BB*NN_-1
  const int t = threadIdx.x;
  const bool second = row >= BB * NN_;
  const float* z = second ? z2 : z1;
  const size_t inBase = (size_t)(second ? row - BB * NN_ : row) * DD + t;
  float v = z[inBase];
  float ss = v * v;
#pragma unroll
  for (int o = 32; o; o >>= 1) ss += __shfl_xor(ss, o);
  __shared__ float par[4];
  if ((t & 63) == 0) par[t >> 6] = ss;
  __syncthreads();
  float tot = par[0] + par[1] + par[2] + par[3];
  znAll[(size_t)row * DD + t] = f2b(v / (sqrtf(tot) + 1e-12f));
}

// ---------------- MFMA NT GEMM, direct global->register fragments (no LDS in loop) ----------------
// C = U * V^T, U:[N][K], V:[N][K] bf16. Flat 1024-block grid, XCD-batch-affinity decode.
// MODE 0: store bf16 C
// MODE 1: store bf16 C + denR[row] += sum_col exp(c*INV_T) skipping row==col
// MODE 2: no store; denR += row-sums of exp, denC += col-sums of exp (S21 = S12^T)
// MODE 3: store C = bf16( acc + add1[pos] + add2[pos] )
// MODE 4: store bf16 C and C^T (LDS-bounce transposed store)
template <int MODE, int K>
__global__ __launch_bounds__(256) void k_gemm_nt(const ushort* __restrict__ U, const ushort* __restrict__ V,
                                                 ushort* __restrict__ C, const ushort* __restrict__ add1,
                                                 const ushort* __restrict__ add2, float* __restrict__ denR,
                                                 float* __restrict__ denC, ushort* __restrict__ Ct) {
  const int t = threadIdx.x;
  // --- XCD-affinity decode: block i -> XCD i&7, each XCD owns 2 whole batches ---
  const int fid = blockIdx.x;
  const int xcd = fid & 7, j = fid >> 3;
  const int b = (xcd << 1) | (j >> 6);
  const int jj = j & 63;
  const int row0 = (jj >> 3) << 7, col0 = (jj & 7) << 7;

  const size_t ub = (size_t)b * NN_ * K;
  const size_t cb = (size_t)b * NN_ * NN_;
  const int lane = t & 63, wv = t >> 6;
  const int wr = wv >> 1, wc = wv & 1;
  const int l15 = lane & 15, slot = lane >> 4;

  // Per-lane fragment base pointers: frag element = row (l15), k (slot*8 .. +8).
  const ushort* pA[4];
  const ushort* pB[4];
#pragma unroll
  for (int f = 0; f < 4; ++f) {
    pA[f] = U + ub + (size_t)(row0 + (wr << 6) + (f << 4) + l15) * K + (slot << 3);
    pB[f] = V + ub + (size_t)(col0 + (wc << 6) + (f << 4) + l15) * K + (slot << 3);
  }

  f32x4 acc[4][4];
#pragma unroll
  for (int i = 0; i < 4; ++i)
#pragma unroll
    for (int jx = 0; jx < 4; ++jx)
#pragma unroll
      for (int e = 0; e < 4; ++e) acc[i][jx][e] = 0.f;

  constexpr int NS = K / 32;  // K-steps (8 or 32), even
  bf16x8 aX[4], bX[4], aY[4], bY[4];

#define LOADG(av, bv, s)                                   \
  {                                                        \
    _Pragma("unroll") for (int f = 0; f < 4; ++f) {        \
      av[f] = *(const bf16x8*)(pA[f] + (s) * 32);          \
      bv[f] = *(const bf16x8*)(pB[f] + (s) * 32);          \
    }                                                      \
  }
#define MFMAG(av, bv)                                                                                 \
  {                                                                                                   \
    _Pragma("unroll") for (int fr = 0; fr < 4; ++fr)                                                  \
        _Pragma("unroll") for (int fc = 0; fc < 4; ++fc) acc[fr][fc] =                                \
            __builtin_amdgcn_mfma_f32_16x16x32_bf16(av[fr], bv[fc], acc[fr][fc], 0, 0, 0);            \
  }

  LOADG(aX, bX, 0)
#pragma unroll
  for (int s = 0; s < NS; s += 2) {
    LOADG(aY, bY, s + 1)
    MFMAG(aX, bX)
    if (s + 2 < NS) LOADG(aX, bX, s + 2)
    MFMAG(aY, bY)
  }
#undef LOADG
#undef MFMAG

  // Epilogue. C/D layout (m89-verified): col = lane&15, row = (lane>>4)*4 + reg.
  if constexpr (MODE == 2) {
    float colp[4] = {0.f, 0.f, 0.f, 0.f};
#pragma unroll
    for (int fr = 0; fr < 4; ++fr) {
#pragma unroll
      for (int jx = 0; jx < 4; ++jx) {
        const int grow = row0 + (wr << 6) + (fr << 4) + (slot << 2) + jx;
        float rs = 0.f;
#pragma unroll
        for (int fc = 0; fc < 4; ++fc) {
          const float e = expf(acc[fr][fc][jx] * INV_T);
          rs += e;
          colp[fc] += e;
        }
#pragma unroll
        for (int o = 1; o < 16; o <<= 1) rs += __shfl_xor(rs, o);
        if (l15 == 0) atomicAdd(&denR[(size_t)b * NN_ + grow], rs);
      }
    }
#pragma unroll
    for (int fc = 0; fc < 4; ++fc) {
      float cs = colp[fc];
      cs += __shfl_xor(cs, 16);
      cs += __shfl_xor(cs, 32);
      if (slot == 0) atomicAdd(&denC[(size_t)b * NN_ + col0 + (wc << 6) + (fc << 4) + l15], cs);
    }
  } else {
    if constexpr (MODE == 4) {
      __shared__ ushort tb[128][136];  // C^T bounce tile, padded stride
#pragma unroll
      for (int fr = 0; fr < 4; ++fr) {
#pragma unroll
        for (int jx = 0; jx < 4; ++jx) {
          const int lrow = (wr << 6) + (fr << 4) + (slot << 2) + jx;
          const int grow = row0 + lrow;
#pragma unroll
          for (int fc = 0; fc < 4; ++fc) {
            const int lcol = (wc << 6) + (fc << 4) + l15;
            const ushort h = f2b(acc[fr][fc][jx]);
            C[cb + (size_t)grow * NN_ + col0 + lcol] = h;
            tb[lcol][lrow] = h;
          }
        }
      }
      __syncthreads();
      // coalesced transposed store: C^T tile origin (col0, row0)
#pragma unroll
      for (int rep = 0; rep < 8; ++rep) {
        const int cid = rep * 256 + t;       // 0..2047
        const int r = cid >> 4;              // 0..127  (C^T row = local col)
        const int c8 = (cid & 15) << 3;      // 0..120
        *(uint4*)&Ct[cb + (size_t)(col0 + r) * NN_ + row0 + c8] = *(const uint4*)&tb[r][c8];
      }
    } else {
#pragma unroll
      for (int fr = 0; fr < 4; ++fr) {
#pragma unroll
        for (int jx = 0; jx < 4; ++jx) {
          const int grow = row0 + (wr << 6) + (fr << 4) + (slot << 2) + jx;
          float rs = 0.f;
#pragma unroll
          for (int fc = 0; fc < 4; ++fc) {
            const int gcol = col0 + (wc << 6) + (fc << 4) + l15;
            const float v = acc[fr][fc][jx];
            const size_t idx = cb + (size_t)grow * NN_ + gcol;
            if constexpr (MODE == 0) {
              C[idx] = f2b(v);
            } else if constexpr (MODE == 1) {
              C[idx] = f2b(v);
              if (grow != gcol) rs += expf(v * INV_T);
            } else {  // MODE 3
              C[idx] = f2b(v + b2f(add1[idx]) + b2f(add2[idx]));
            }
          }
          if constexpr (MODE == 1) {
#pragma unroll
            for (int o = 1; o < 16; o <<= 1) rs += __shfl_xor(rs, o);
            if (l15 == 0) atomicAdd(&denR[(size_t)b * NN_ + grow], rs);
          }
        }
      }
    }
  }
}

// ---------------- in-place row softmax on bf16 matrix ----------------
__global__ __launch_bounds__(256) void k_softmax(ushort* __restrict__ S) {
  const size_t row = blockIdx.x;
  const int t = threadIdx.x;
  ushort* sr = S + row * (size_t)NN_;
  ushort4 u = *(const ushort4*)&sr[t << 2];
  float v0 = b2f(u.x), v1 = b2f(u.y), v2 = b2f(u.z), v3 = b2f(u.w);
  float m = fmaxf(fmaxf(v0, v1), fmaxf(v2, v3));
#pragma unroll
  for (int o = 32; o; o >>= 1) m = fmaxf(m, __shfl_xor(m, o));
  __shared__ float pm[4], ps[4];
  if ((t & 63) == 0) pm[t >> 6] = m;
  __syncthreads();
  m = fmaxf(fmaxf(pm[0], pm[1]), fmaxf(pm[2], pm[3]));
  const float e0 = expf(v0 - m), e1 = expf(v1 - m), e2 = expf(v2 - m), e3 = expf(v3 - m);
  float s = e0 + e1 + e2 + e3;
#pragma unroll
  for (int o = 32; o; o >>= 1) s += __shfl_xor(s, o);
  if ((t & 63) == 0) ps[t >> 6] = s;
  __syncthreads();
  s = ps[0] + ps[1] + ps[2] + ps[3];
  const float inv = 1.0f / s;
  ushort4 w;
  w.x = f2b(e0 * inv); w.y = f2b(e1 * inv); w.z = f2b(e2 * inv); w.w = f2b(e3 * inv);
  *(ushort4*)&sr[t << 2] = w;
}

// ---------------- bf16 NxN transpose (per batch), 64x64 tiles ----------------
__global__ __launch_bounds__(256) void k_transpose(const ushort* __restrict__ in, ushort* __restrict__ out) {
  const int b = blockIdx.z;
  const size_t mb = (size_t)b * NN_ * NN_;
  const int bx = blockIdx.x, by = blockIdx.y;
  __shared__ ushort tl[64][65];
  const int t = threadIdx.x;
  const int r = t >> 3, c = (t & 7) << 3;
#pragma unroll
  for (int h = 0; h < 2; ++h) {
    const int rr = r + h * 32;
    uint4 v = *(const uint4*)&in[mb + (size_t)(by * 64 + rr) * NN_ + bx * 64 + c];
    const ushort* pv = (const ushort*)&v;
#pragma unroll
    for (int e = 0; e < 8; ++e) tl[rr][c + e] = pv[e];
  }
  __syncthreads();
#pragma unroll
  for (int h = 0; h < 2; ++h) {
    const int rr = r + h * 32;
    ushort tmp[8];
#pragma unroll
    for (int e = 0; e < 8; ++e) tmp[e] = tl[c + e][rr];
    *(uint4*)&out[mb + (size_t)(bx * 64 + rr) * NN_ + by * 64 + c] = *(const uint4*)tmp;
  }
}

// ---------------- per-row top-5 + numerator + loss ----------------
__global__ __launch_bounds__(64) void k_topk(const ushort* __restrict__ Ssum, const ushort* __restrict__ znS,
                                             const ushort* __restrict__ znO, const float* __restrict__ den,
                                             float* __restrict__ lossRows, int halfOff) {
  const int gid = blockIdx.x;  // b*1024 + i
  const int b = gid >> 10, i = gid & 1023;
  const int lane = threadIdx.x;
  const size_t rowoff = (size_t)gid << 10;

  float sc[16];
#pragma unroll
  for (int tt = 0; tt < 16; ++tt) {
    const int j = tt * 64 + lane;
    const float a = b2f(Ssum[rowoff + j]);
    const float dd = (float)(j - i);
    const float pw = expf(-dd * dd * 0.125f);
    sc[tt] = 0.5f * pw + a * (0.5f / 3.0f);
  }

  float pv[5]; int pidx[5];
#pragma unroll
  for (int it = 0; it < 5; ++it) {
    float bv = -INFINITY; int bi = 0x7fffffff;
#pragma unroll
    for (int tt = 0; tt < 16; ++tt) {
      const int j = tt * 64 + lane;
      if (sc[tt] > bv || (sc[tt] == bv && j < bi)) { bv = sc[tt]; bi = j; }
    }
#pragma unroll
    for (int o = 32; o; o >>= 1) {
      const float ov = __shfl_xor(bv, o);
      const int oi = __shfl_xor(bi, o);
      if (ov > bv || (ov == bv && oi < bi)) { bv = ov; bi = oi; }
    }
    pv[it] = bv; pidx[it] = bi;
    if ((bi & 63) == lane) sc[bi >> 6] = -INFINITY;
  }

  const ushort4 qr = *(const ushort4*)&znS[((size_t)b * NN_ + i) * DD + (lane << 2)];
  const float q0 = b2f(qr.x), q1 = b2f(qr.y), q2 = b2f(qr.z), q3 = b2f(qr.w);

  auto rowdot = [&](int jr) -> float {
    const ushort4 orr = *(const ushort4*)&znO[((size_t)b * NN_ + jr) * DD + (lane << 2)];
    float p = q0 * b2f(orr.x) + q1 * b2f(orr.y) + q2 * b2f(orr.z) + q3 * b2f(orr.w);
#pragma unroll
    for (int o = 32; o; o >>= 1) p += __shfl_xor(p, o);
    return p;
  };

  float num = expf(rowdot(i) * INV_T);  // strong term
#pragma unroll
  for (int it = 0; it < 5; ++it)
    if (pidx[it] != i) num += pv[it] * expf(rowdot(pidx[it]) * INV_T);

  if (lane == 0) {
    const float dn = den[(size_t)b * NN_ + i];
    lossRows[(size_t)b * (2 * NN_) + halfOff + i] = -logf(num / (dn + 1e-9f) + 1e-9f);
  }
}

// ---------------- final mean ----------------
__global__ __launch_bounds__(256) void k_final(const float* __restrict__ lossRows, float* __restrict__ out) {
  const int t = threadIdx.x;
  float s = 0.f;
  for (int idx = t; idx < BB * 2 * NN_; idx += 256) s += lossRows[idx];
#pragma unroll
  for (int o = 32; o; o >>= 1) s += __shfl_xor(s, o);
  __shared__ float p[4];
  if ((t & 63) == 0) p[t >> 6] = s;
  __syncthreads();
  if (t == 0) out[0] = (p[0] + p[1] + p[2] + p[3]) / (float)(BB * 2 * NN_);
}

extern "C" void kernel_launch(void* const* d_in, const int* in_sizes, int n_in, void* d_out, int out_size,
                              void* d_ws, size_t ws_size, hipStream_t stream) {
  const float* z1 = (const float*)d_in[0];
  const float* z2 = (const float*)d_in[1];
  float* out = (float*)d_out;

  const size_t nzd = (size_t)BB * NN_ * DD;
  const size_t nnn = (size_t)BB * NN_ * NN_;

  ushort* zn1 = (ushort*)d_ws;
  ushort* zn2 = zn1 + nzd;
  ushort* X = zn2 + nzd;
  ushort* Y = X + nnn;
  ushort* Z = Y + nnn;
  float* den1 = (float*)(Z + nnn);
  float* den2 = den1 + (size_t)BB * NN_;
  float* lossRows = den2 + (size_t)BB * NN_;
  ushort* W = (ushort*)(lossRows + 2 * (size_t)BB * NN_);

  const size_t base = 2 * nzd * 2 + 3 * nnn * 2 + 4 * (size_t)BB * NN_ * 4;
  if (ws_size < base) return;  // fail cleanly instead of faulting
  const bool useW = ws_size >= base + nnn * 2;

  dim3 blk(256);
  const int gFlat = (NN_ / 128) * (NN_ / 128) * BB;  // 1024
  dim3 gT(NN_ / 64, NN_ / 64, BB);

  hipMemsetAsync(den1, 0, 2 * (size_t)BB * NN_ * 4, stream);

  k_norm<<<2 * BB * NN_, blk, 0, stream>>>(z1, z2, zn1);

  if (useW) {
    // half 2: X = S22 (+den2), softmax -> A2
    k_gemm_nt<1, DD><<<gFlat, blk, 0, stream>>>(zn2, zn2, X, nullptr, nullptr, den2, nullptr, nullptr);
    k_softmax<<<BB * NN_, blk, 0, stream>>>(X);
    k_transpose<<<gT, blk, 0, stream>>>(X, Y);                                                       // Y = A2^T
    k_gemm_nt<4, NN_><<<gFlat, blk, 0, stream>>>(X, Y, Z, nullptr, nullptr, nullptr, nullptr, W);    // Z = A2^2, W = (A2^2)^T
    k_gemm_nt<3, NN_><<<gFlat, blk, 0, stream>>>(Z, W, X, X, Z, nullptr, nullptr, nullptr);          // X = sum2

    // cross den contributions (S21 = S12^T)
    k_gemm_nt<2, DD><<<gFlat, blk, 0, stream>>>(zn1, zn2, nullptr, nullptr, nullptr, den1, den2, nullptr);

    // half 1: Z = S11 (+den1), softmax -> A1
    k_gemm_nt<1, DD><<<gFlat, blk, 0, stream>>>(zn1, zn1, Z, nullptr, nullptr, den1, nullptr, nullptr);
    k_softmax<<<BB * NN_, blk, 0, stream>>>(Z);

    k_topk<<<BB * NN_, dim3(64), 0, stream>>>(X, zn1, zn2, den1, lossRows, 0);

    k_transpose<<<gT, blk, 0, stream>>>(Z, Y);                                                       // Y = A1^T
    k_gemm_nt<4, NN_><<<gFlat, blk, 0, stream>>>(Z, Y, X, nullptr, nullptr, nullptr, nullptr, W);    // X = A1^2, W = (A1^2)^T
    k_gemm_nt<3, NN_><<<gFlat, blk, 0, stream>>>(X, W, Z, Z, X, nullptr, nullptr, nullptr);          // Z = sum1

    k_topk<<<BB * NN_, dim3(64), 0, stream>>>(Z, zn2, zn1, den2, lossRows, NN_);
  } else {
    // fallback: round-3 sequence with transposes
    k_gemm_nt<1, DD><<<gFlat, blk, 0, stream>>>(zn2, zn2, X, nullptr, nullptr, den2, nullptr, nullptr);
    k_softmax<<<BB * NN_, blk, 0, stream>>>(X);
    k_transpose<<<gT, blk, 0, stream>>>(X, Y);
    k_gemm_nt<0, NN_><<<gFlat, blk, 0, stream>>>(X, Y, Z, nullptr, nullptr, nullptr, nullptr, nullptr);
    k_transpose<<<gT, blk, 0, stream>>>(Z, Y);
    k_gemm_nt<3, NN_><<<gFlat, blk, 0, stream>>>(Z, Y, X, X, Z, nullptr, nullptr, nullptr);
    k_gemm_nt<2, DD><<<gFlat, blk, 0, stream>>>(zn1, zn2, nullptr, nullptr, nullptr, den1, den2, nullptr);
    k_gemm_nt<1, DD><<<gFlat, blk, 0, stream>>>(zn1, zn1, Z, nullptr, nullptr, den1, nullptr, nullptr);
    k_softmax<<<BB * NN_, blk, 0, stream>>>(Z);
    k_topk<<<BB * NN_, dim3(64), 0, stream>>>(X, zn1, zn2, den1, lossRows, 0);
    k_transpose<<<gT, blk, 0, stream>>>(Z, Y);
    k_gemm_nt<0, NN_><<<gFlat, blk, 0, stream>>>(Z, Y, X, nullptr, nullptr, nullptr, nullptr, nullptr);
    k_transpose<<<gT, blk, 0, stream>>>(X, Y);
    k_gemm_nt<3, NN_><<<gFlat, blk, 0, stream>>>(X, Y, Z, Z, X, nullptr, nullptr, nullptr);
    k_topk<<<BB * NN_, dim3(64), 0, stream>>>(Z, zn2, zn1, den2, lossRows, NN_);
  }

  k_final<<<1, blk, 0, stream>>>(lossRows, out);
}

// Round 5
// 537.401 us; speedup vs baseline: 1.6836x; 1.6836x over previous
//
#include <hip/hip_runtime.h>
#include <cmath>
#include <cstdint>

#define BB 16
#define NN_ 1024
#define DD 256

constexpr float INV_T = 1.0f / 0.07f;

typedef __attribute__((ext_vector_type(8))) short bf16x8;
typedef __attribute__((ext_vector_type(4))) float f32x4;

static __device__ __forceinline__ float b2f(ushort u) {
  union { uint i; float f; } c; c.i = ((uint)u) << 16; return c.f;
}
static __device__ __forceinline__ ushort f2b(float f) {
  union { float f; uint i; } c; c.f = f;
  uint r = c.i + 0x7fffu + ((c.i >> 16) & 1u);
  return (ushort)(r >> 16);
}

// async global->LDS, 16B per lane, LDS dest = wave-uniform base + lane*16
static __device__ __forceinline__ void gload16(const void* g, void* l) {
  __builtin_amdgcn_global_load_lds((const __attribute__((address_space(1))) unsigned int*)g,
                                   (__attribute__((address_space(3))) unsigned int*)l, 16, 0, 0);
}

// ---------------- row normalize: z(f32) -> zn(bf16), both halves in one launch ----------------
__global__ __launch_bounds__(256) void k_norm(const float* __restrict__ z1, const float* __restrict__ z2,
                                              ushort* __restrict__ znAll) {
  const int row = blockIdx.x;  // 0 .. 2*BB*NN_-1
  const int t = threadIdx.x;
  const bool second = row >= BB * NN_;
  const float* z = second ? z2 : z1;
  const size_t inBase = (size_t)(second ? row - BB * NN_ : row) * DD + t;
  float v = z[inBase];
  float ss = v * v;
#pragma unroll
  for (int o = 32; o; o >>= 1) ss += __shfl_xor(ss, o);
  __shared__ float par[4];
  if ((t & 63) == 0) par[t >> 6] = ss;
  __syncthreads();
  float tot = par[0] + par[1] + par[2] + par[3];
  znAll[(size_t)row * DD + t] = f2b(v / (sqrtf(tot) + 1e-12f));
}

// ---------------- MFMA NT GEMM, global_load_lds staging (m97 structure) ----------------
// C = U * V^T, U:[N][K], V:[N][K] bf16. Flat 1024-block grid, XCD-batch-affinity decode.
// LDS linear [128][32]; k-group swizzle kg ^= (row>>1)&3 applied on the GLOBAL source side
// (m173 pattern) and on the fragment-read side, so staging stays wave-linear.
// MODE 0: store bf16 C
// MODE 1: store bf16 C + denR[row] += sum_col exp(c*INV_T) skipping row==col
// MODE 2: no store; denR += row-sums of exp, denC += col-sums of exp (S21 = S12^T)
// MODE 3: store C = bf16( acc + add1[pos] + add2[pos] )
// MODE 4: store bf16 C and C^T (LDS-bounce transposed store)
template <int MODE, int K>
__global__ __launch_bounds__(256) void k_gemm_nt(const ushort* __restrict__ U, const ushort* __restrict__ V,
                                                 ushort* __restrict__ C, const ushort* __restrict__ add1,
                                                 const ushort* __restrict__ add2, float* __restrict__ denR,
                                                 float* __restrict__ denC, ushort* __restrict__ Ct) {
  __shared__ __align__(16) ushort As[128][32];
  __shared__ __align__(16) ushort Bs[128][32];
  const int t = threadIdx.x;
  // --- XCD-affinity decode: block i -> XCD i&7, each XCD owns 2 whole batches ---
  const int fid = blockIdx.x;
  const int xcd = fid & 7, j = fid >> 3;
  const int b = (xcd << 1) | (j >> 6);
  const int jj = j & 63;
  const int row0 = (jj >> 3) << 7, col0 = (jj & 7) << 7;

  const size_t ub = (size_t)b * NN_ * K;
  const size_t cb = (size_t)b * NN_ * NN_;
  const int lane = t & 63, w = t >> 6;
  const int wr = w >> 1, wc = w & 1;
  const int l15 = lane & 15, slot = lane >> 4;

  // staging: wave w owns rows w*32..w*32+31 of both tiles; lane -> (row r0+lane/4, 16B chunk)
  const int sRow = lane >> 2;                                  // 0..15
  const int kg = (lane & 3) ^ ((lane >> 3) & 3);               // swizzled k-group to fetch
  const int sCol = kg << 3;                                    // shorts
  const ushort* gA0 = U + ub + (size_t)(row0 + (w << 5) + sRow) * K + sCol;
  const ushort* gA1 = gA0 + (size_t)16 * K;
  const ushort* gB0 = V + ub + (size_t)(col0 + (w << 5) + sRow) * K + sCol;
  const ushort* gB1 = gB0 + (size_t)16 * K;
  ushort* lA0 = &As[w << 5][0];
  ushort* lA1 = &As[(w << 5) + 16][0];
  ushort* lB0 = &Bs[w << 5][0];
  ushort* lB1 = &Bs[(w << 5) + 16][0];

  f32x4 acc[4][4];
#pragma unroll
  for (int i = 0; i < 4; ++i)
#pragma unroll
    for (int jx = 0; jx < 4; ++jx)
#pragma unroll
      for (int e = 0; e < 4; ++e) acc[i][jx][e] = 0.f;

  for (int k0 = 0; k0 < K; k0 += 32) {
    gload16(gA0 + k0, lA0);
    gload16(gA1 + k0, lA1);
    gload16(gB0 + k0, lB0);
    gload16(gB1 + k0, lB1);
    __syncthreads();  // drains vmcnt -> staged data visible to all waves
    bf16x8 af[4], bfv[4];
#pragma unroll
    for (int fr = 0; fr < 4; ++fr) {
      const int r = (wr << 6) + (fr << 4) + l15;
      af[fr] = *(const bf16x8*)&As[r][(slot ^ ((r >> 1) & 3)) << 3];
    }
#pragma unroll
    for (int fc = 0; fc < 4; ++fc) {
      const int r = (wc << 6) + (fc << 4) + l15;
      bfv[fc] = *(const bf16x8*)&Bs[r][(slot ^ ((r >> 1) & 3)) << 3];
    }
#pragma unroll
    for (int fr = 0; fr < 4; ++fr)
#pragma unroll
      for (int fc = 0; fc < 4; ++fc)
        acc[fr][fc] = __builtin_amdgcn_mfma_f32_16x16x32_bf16(af[fr], bfv[fc], acc[fr][fc], 0, 0, 0);
    __syncthreads();  // all waves done reading before next stage overwrites
  }

  // Epilogue. C/D layout (m89-verified): col = lane&15, row = (lane>>4)*4 + reg.
  if constexpr (MODE == 2) {
    float colp[4] = {0.f, 0.f, 0.f, 0.f};
#pragma unroll
    for (int fr = 0; fr < 4; ++fr) {
#pragma unroll
      for (int jx = 0; jx < 4; ++jx) {
        const int grow = row0 + (wr << 6) + (fr << 4) + (slot << 2) + jx;
        float rs = 0.f;
#pragma unroll
        for (int fc = 0; fc < 4; ++fc) {
          const float e = expf(acc[fr][fc][jx] * INV_T);
          rs += e;
          colp[fc] += e;
        }
#pragma unroll
        for (int o = 1; o < 16; o <<= 1) rs += __shfl_xor(rs, o);
        if (l15 == 0) atomicAdd(&denR[(size_t)b * NN_ + grow], rs);
      }
    }
#pragma unroll
    for (int fc = 0; fc < 4; ++fc) {
      float cs = colp[fc];
      cs += __shfl_xor(cs, 16);
      cs += __shfl_xor(cs, 32);
      if (slot == 0) atomicAdd(&denC[(size_t)b * NN_ + col0 + (wc << 6) + (fc << 4) + l15], cs);
    }
  } else {
    if constexpr (MODE == 4) {
      __shared__ ushort tb[128][136];  // C^T bounce tile, padded stride
#pragma unroll
      for (int fr = 0; fr < 4; ++fr) {
#pragma unroll
        for (int jx = 0; jx < 4; ++jx) {
          const int lrow = (wr << 6) + (fr << 4) + (slot << 2) + jx;
          const int grow = row0 + lrow;
#pragma unroll
          for (int fc = 0; fc < 4; ++fc) {
            const int lcol = (wc << 6) + (fc << 4) + l15;
            const ushort h = f2b(acc[fr][fc][jx]);
            C[cb + (size_t)grow * NN_ + col0 + lcol] = h;
            tb[lcol][lrow] = h;
          }
        }
      }
      __syncthreads();
      // coalesced transposed store: C^T tile origin (col0, row0)
#pragma unroll
      for (int rep = 0; rep < 8; ++rep) {
        const int cid = rep * 256 + t;  // 0..2047
        const int r = cid >> 4;         // 0..127  (C^T row = local col)
        const int c8 = (cid & 15) << 3; // 0..120
        *(uint4*)&Ct[cb + (size_t)(col0 + r) * NN_ + row0 + c8] = *(const uint4*)&tb[r][c8];
      }
    } else {
#pragma unroll
      for (int fr = 0; fr < 4; ++fr) {
#pragma unroll
        for (int jx = 0; jx < 4; ++jx) {
          const int grow = row0 + (wr << 6) + (fr << 4) + (slot << 2) + jx;
          float rs = 0.f;
#pragma unroll
          for (int fc = 0; fc < 4; ++fc) {
            const int gcol = col0 + (wc << 6) + (fc << 4) + l15;
            const float v = acc[fr][fc][jx];
            const size_t idx = cb + (size_t)grow * NN_ + gcol;
            if constexpr (MODE == 0) {
              C[idx] = f2b(v);
            } else if constexpr (MODE == 1) {
              C[idx] = f2b(v);
              if (grow != gcol) rs += expf(v * INV_T);
            } else {  // MODE 3
              C[idx] = f2b(v + b2f(add1[idx]) + b2f(add2[idx]));
            }
          }
          if constexpr (MODE == 1) {
#pragma unroll
            for (int o = 1; o < 16; o <<= 1) rs += __shfl_xor(rs, o);
            if (l15 == 0) atomicAdd(&denR[(size_t)b * NN_ + grow], rs);
          }
        }
      }
    }
  }
}

// ---------------- in-place row softmax on bf16 matrix ----------------
__global__ __launch_bounds__(256) void k_softmax(ushort* __restrict__ S) {
  const size_t row = blockIdx.x;
  const int t = threadIdx.x;
  ushort* sr = S + row * (size_t)NN_;
  ushort4 u = *(const ushort4*)&sr[t << 2];
  float v0 = b2f(u.x), v1 = b2f(u.y), v2 = b2f(u.z), v3 = b2f(u.w);
  float m = fmaxf(fmaxf(v0, v1), fmaxf(v2, v3));
#pragma unroll
  for (int o = 32; o; o >>= 1) m = fmaxf(m, __shfl_xor(m, o));
  __shared__ float pm[4], ps[4];
  if ((t & 63) == 0) pm[t >> 6] = m;
  __syncthreads();
  m = fmaxf(fmaxf(pm[0], pm[1]), fmaxf(pm[2], pm[3]));
  const float e0 = expf(v0 - m), e1 = expf(v1 - m), e2 = expf(v2 - m), e3 = expf(v3 - m);
  float s = e0 + e1 + e2 + e3;
#pragma unroll
  for (int o = 32; o; o >>= 1) s += __shfl_xor(s, o);
  if ((t & 63) == 0) ps[t >> 6] = s;
  __syncthreads();
  s = ps[0] + ps[1] + ps[2] + ps[3];
  const float inv = 1.0f / s;
  ushort4 wq;
  wq.x = f2b(e0 * inv); wq.y = f2b(e1 * inv); wq.z = f2b(e2 * inv); wq.w = f2b(e3 * inv);
  *(ushort4*)&sr[t << 2] = wq;
}

// ---------------- bf16 NxN transpose (per batch), 64x64 tiles ----------------
__global__ __launch_bounds__(256) void k_transpose(const ushort* __restrict__ in, ushort* __restrict__ out) {
  const int b = blockIdx.z;
  const size_t mb = (size_t)b * NN_ * NN_;
  const int bx = blockIdx.x, by = blockIdx.y;
  __shared__ ushort tl[64][65];
  const int t = threadIdx.x;
  const int r = t >> 3, c = (t & 7) << 3;
#pragma unroll
  for (int h = 0; h < 2; ++h) {
    const int rr = r + h * 32;
    uint4 v = *(const uint4*)&in[mb + (size_t)(by * 64 + rr) * NN_ + bx * 64 + c];
    const ushort* pv = (const ushort*)&v;
#pragma unroll
    for (int e = 0; e < 8; ++e) tl[rr][c + e] = pv[e];
  }
  __syncthreads();
#pragma unroll
  for (int h = 0; h < 2; ++h) {
    const int rr = r + h * 32;
    ushort tmp[8];
#pragma unroll
    for (int e = 0; e < 8; ++e) tmp[e] = tl[c + e][rr];
    *(uint4*)&out[mb + (size_t)(bx * 64 + rr) * NN_ + by * 64 + c] = *(const uint4*)tmp;
  }
}

// ---------------- per-row top-5 + numerator + loss ----------------
__global__ __launch_bounds__(64) void k_topk(const ushort* __restrict__ Ssum, const ushort* __restrict__ znS,
                                             const ushort* __restrict__ znO, const float* __restrict__ den,
                                             float* __restrict__ lossRows, int halfOff) {
  const int gid = blockIdx.x;  // b*1024 + i
  const int b = gid >> 10, i = gid & 1023;
  const int lane = threadIdx.x;
  const size_t rowoff = (size_t)gid << 10;

  float sc[16];
#pragma unroll
  for (int tt = 0; tt < 16; ++tt) {
    const int j = tt * 64 + lane;
    const float a = b2f(Ssum[rowoff + j]);
    const float dd = (float)(j - i);
    const float pw = expf(-dd * dd * 0.125f);
    sc[tt] = 0.5f * pw + a * (0.5f / 3.0f);
  }

  float pv[5]; int pidx[5];
#pragma unroll
  for (int it = 0; it < 5; ++it) {
    float bv = -INFINITY; int bi = 0x7fffffff;
#pragma unroll
    for (int tt = 0; tt < 16; ++tt) {
      const int j = tt * 64 + lane;
      if (sc[tt] > bv || (sc[tt] == bv && j < bi)) { bv = sc[tt]; bi = j; }
    }
#pragma unroll
    for (int o = 32; o; o >>= 1) {
      const float ov = __shfl_xor(bv, o);
      const int oi = __shfl_xor(bi, o);
      if (ov > bv || (ov == bv && oi < bi)) { bv = ov; bi = oi; }
    }
    pv[it] = bv; pidx[it] = bi;
    if ((bi & 63) == lane) sc[bi >> 6] = -INFINITY;
  }

  const ushort4 qr = *(const ushort4*)&znS[((size_t)b * NN_ + i) * DD + (lane << 2)];
  const float q0 = b2f(qr.x), q1 = b2f(qr.y), q2 = b2f(qr.z), q3 = b2f(qr.w);

  auto rowdot = [&](int jr) -> float {
    const ushort4 orr = *(const ushort4*)&znO[((size_t)b * NN_ + jr) * DD + (lane << 2)];
    float p = q0 * b2f(orr.x) + q1 * b2f(orr.y) + q2 * b2f(orr.z) + q3 * b2f(orr.w);
#pragma unroll
    for (int o = 32; o; o >>= 1) p += __shfl_xor(p, o);
    return p;
  };

  float num = expf(rowdot(i) * INV_T);  // strong term
#pragma unroll
  for (int it = 0; it < 5; ++it)
    if (pidx[it] != i) num += pv[it] * expf(rowdot(pidx[it]) * INV_T);

  if (lane == 0) {
    const float dn = den[(size_t)b * NN_ + i];
    lossRows[(size_t)b * (2 * NN_) + halfOff + i] = -logf(num / (dn + 1e-9f) + 1e-9f);
  }
}

// ---------------- final mean ----------------
__global__ __launch_bounds__(256) void k_final(const float* __restrict__ lossRows, float* __restrict__ out) {
  const int t = threadIdx.x;
  float s = 0.f;
  for (int idx = t; idx < BB * 2 * NN_; idx += 256) s += lossRows[idx];
#pragma unroll
  for (int o = 32; o; o >>= 1) s += __shfl_xor(s, o);
  __shared__ float p[4];
  if ((t & 63) == 0) p[t >> 6] = s;
  __syncthreads();
  if (t == 0) out[0] = (p[0] + p[1] + p[2] + p[3]) / (float)(BB * 2 * NN_);
}

extern "C" void kernel_launch(void* const* d_in, const int* in_sizes, int n_in, void* d_out, int out_size,
                              void* d_ws, size_t ws_size, hipStream_t stream) {
  const float* z1 = (const float*)d_in[0];
  const float* z2 = (const float*)d_in[1];
  float* out = (float*)d_out;

  const size_t nzd = (size_t)BB * NN_ * DD;
  const size_t nnn = (size_t)BB * NN_ * NN_;

  ushort* zn1 = (ushort*)d_ws;
  ushort* zn2 = zn1 + nzd;
  ushort* X = zn2 + nzd;
  ushort* Y = X + nnn;
  ushort* Z = Y + nnn;
  float* den1 = (float*)(Z + nnn);
  float* den2 = den1 + (size_t)BB * NN_;
  float* lossRows = den2 + (size_t)BB * NN_;
  ushort* W = (ushort*)(lossRows + 2 * (size_t)BB * NN_);

  const size_t base = 2 * nzd * 2 + 3 * nnn * 2 + 4 * (size_t)BB * NN_ * 4;
  if (ws_size < base) return;  // fail cleanly instead of faulting
  const bool useW = ws_size >= base + nnn * 2;

  dim3 blk(256);
  const int gFlat = (NN_ / 128) * (NN_ / 128) * BB;  // 1024
  dim3 gT(NN_ / 64, NN_ / 64, BB);

  hipMemsetAsync(den1, 0, 2 * (size_t)BB * NN_ * 4, stream);

  k_norm<<<2 * BB * NN_, blk, 0, stream>>>(z1, z2, zn1);

  if (useW) {
    // half 2: X = S22 (+den2), softmax -> A2
    k_gemm_nt<1, DD><<<gFlat, blk, 0, stream>>>(zn2, zn2, X, nullptr, nullptr, den2, nullptr, nullptr);
    k_softmax<<<BB * NN_, blk, 0, stream>>>(X);
    k_transpose<<<gT, blk, 0, stream>>>(X, Y);                                                       // Y = A2^T
    k_gemm_nt<4, NN_><<<gFlat, blk, 0, stream>>>(X, Y, Z, nullptr, nullptr, nullptr, nullptr, W);    // Z = A2^2, W = (A2^2)^T
    k_gemm_nt<3, NN_><<<gFlat, blk, 0, stream>>>(Z, W, X, X, Z, nullptr, nullptr, nullptr);          // X = sum2

    // cross den contributions (S21 = S12^T)
    k_gemm_nt<2, DD><<<gFlat, blk, 0, stream>>>(zn1, zn2, nullptr, nullptr, nullptr, den1, den2, nullptr);

    // half 1: Z = S11 (+den1), softmax -> A1
    k_gemm_nt<1, DD><<<gFlat, blk, 0, stream>>>(zn1, zn1, Z, nullptr, nullptr, den1, nullptr, nullptr);
    k_softmax<<<BB * NN_, blk, 0, stream>>>(Z);

    k_topk<<<BB * NN_, dim3(64), 0, stream>>>(X, zn1, zn2, den1, lossRows, 0);

    k_transpose<<<gT, blk, 0, stream>>>(Z, Y);                                                       // Y = A1^T
    k_gemm_nt<4, NN_><<<gFlat, blk, 0, stream>>>(Z, Y, X, nullptr, nullptr, nullptr, nullptr, W);    // X = A1^2, W = (A1^2)^T
    k_gemm_nt<3, NN_><<<gFlat, blk, 0, stream>>>(X, W, Z, Z, X, nullptr, nullptr, nullptr);          // Z = sum1

    k_topk<<<BB * NN_, dim3(64), 0, stream>>>(Z, zn2, zn1, den2, lossRows, NN_);
  } else {
    // fallback: round-3 sequence with transposes
    k_gemm_nt<1, DD><<<gFlat, blk, 0, stream>>>(zn2, zn2, X, nullptr, nullptr, den2, nullptr, nullptr);
    k_softmax<<<BB * NN_, blk, 0, stream>>>(X);
    k_transpose<<<gT, blk, 0, stream>>>(X, Y);
    k_gemm_nt<0, NN_><<<gFlat, blk, 0, stream>>>(X, Y, Z, nullptr, nullptr, nullptr, nullptr, nullptr);
    k_transpose<<<gT, blk, 0, stream>>>(Z, Y);
    k_gemm_nt<3, NN_><<<gFlat, blk, 0, stream>>>(Z, Y, X, X, Z, nullptr, nullptr, nullptr);
    k_gemm_nt<2, DD><<<gFlat, blk, 0, stream>>>(zn1, zn2, nullptr, nullptr, nullptr, den1, den2, nullptr);
    k_gemm_nt<1, DD><<<gFlat, blk, 0, stream>>>(zn1, zn1, Z, nullptr, nullptr, den1, nullptr, nullptr);
    k_softmax<<<BB * NN_, blk, 0, stream>>>(Z);
    k_topk<<<BB * NN_, dim3(64), 0, stream>>>(X, zn1, zn2, den1, lossRows, 0);
    k_transpose<<<gT, blk, 0, stream>>>(Z, Y);
    k_gemm_nt<0, NN_><<<gFlat, blk, 0, stream>>>(Z, Y, X, nullptr, nullptr, nullptr, nullptr, nullptr);
    k_transpose<<<gT, blk, 0, stream>>>(X, Y);
    k_gemm_nt<3, NN_><<<gFlat, blk, 0, stream>>>(X, Y, Z, Z, X, nullptr, nullptr, nullptr);
    k_topk<<<BB * NN_, dim3(64), 0, stream>>>(Z, zn2, zn1, den2, lossRows, NN_);
  }

  k_final<<<1, blk, 0, stream>>>(lossRows, out);
}

// Round 6
// 406.027 us; speedup vs baseline: 2.2284x; 1.3236x over previous
//
#include <hip/hip_runtime.h>
#include <cmath>
#include <cstdint>

#define BB 16
#define NN_ 1024
#define DD 256

constexpr float INV_T = 1.0f / 0.07f;

typedef __attribute__((ext_vector_type(8))) short bf16x8;
typedef __attribute__((ext_vector_type(4))) float f32x4;

static __device__ __forceinline__ float b2f(ushort u) {
  union { uint i; float f; } c; c.i = ((uint)u) << 16; return c.f;
}
static __device__ __forceinline__ ushort f2b(float f) {
  union { float f; uint i; } c; c.f = f;
  uint r = c.i + 0x7fffu + ((c.i >> 16) & 1u);
  return (ushort)(r >> 16);
}

// async global->LDS, 16B per lane, LDS dest = wave-uniform base + lane*16
static __device__ __forceinline__ void gload16(const void* g, void* l) {
  __builtin_amdgcn_global_load_lds((const __attribute__((address_space(1))) unsigned int*)g,
                                   (__attribute__((address_space(3))) unsigned int*)l, 16, 0, 0);
}

// ---------------- row normalize: z(f32) -> zn(bf16), both halves in one launch ----------------
__global__ __launch_bounds__(256) void k_norm(const float* __restrict__ z1, const float* __restrict__ z2,
                                              ushort* __restrict__ znAll) {
  const int row = blockIdx.x;  // 0 .. 2*BB*NN_-1
  const int t = threadIdx.x;
  const bool second = row >= BB * NN_;
  const float* z = second ? z2 : z1;
  const size_t inBase = (size_t)(second ? row - BB * NN_ : row) * DD + t;
  float v = z[inBase];
  float ss = v * v;
#pragma unroll
  for (int o = 32; o; o >>= 1) ss += __shfl_xor(ss, o);
  __shared__ float par[4];
  if ((t & 63) == 0) par[t >> 6] = ss;
  __syncthreads();
  float tot = par[0] + par[1] + par[2] + par[3];
  znAll[(size_t)row * DD + t] = f2b(v / (sqrtf(tot) + 1e-12f));
}

// ---------------- MFMA NT GEMM, global_load_lds staging (m97 structure) ----------------
// C = U * V^T, U:[N][K], V:[N][K] bf16. Flat 1024-block grid, XCD-batch-affinity decode.
// MODE 1: store bf16 C + denR[row] += sum_col exp(c*INV_T) skipping row==col
// MODE 2: no store; denR += row-sums of exp, denC += col-sums of exp (S21 = S12^T)
// MODE 4: store bf16 C and C^T (LDS-bounce transposed store)
template <int MODE, int K>
__global__ __launch_bounds__(256) void k_gemm_nt(const ushort* __restrict__ U, const ushort* __restrict__ V,
                                                 ushort* __restrict__ C, float* __restrict__ denR,
                                                 float* __restrict__ denC, ushort* __restrict__ Ct) {
  __shared__ __align__(16) ushort As[128][32];
  __shared__ __align__(16) ushort Bs[128][32];
  const int t = threadIdx.x;
  // --- XCD-affinity decode: block i -> XCD i&7, each XCD owns 2 whole batches ---
  const int fid = blockIdx.x;
  const int xcd = fid & 7, j = fid >> 3;
  const int b = (xcd << 1) | (j >> 6);
  const int jj = j & 63;
  const int row0 = (jj >> 3) << 7, col0 = (jj & 7) << 7;

  const size_t ub = (size_t)b * NN_ * K;
  const size_t cb = (size_t)b * NN_ * NN_;
  const int lane = t & 63, w = t >> 6;
  const int wr = w >> 1, wc = w & 1;
  const int l15 = lane & 15, slot = lane >> 4;

  // staging: wave w owns rows w*32..w*32+31 of both tiles
  const int sRow = lane >> 2;                     // 0..15
  const int kg = (lane & 3) ^ ((lane >> 3) & 3);  // swizzled k-group (source side, m173 pattern)
  const int sCol = kg << 3;
  const ushort* gA0 = U + ub + (size_t)(row0 + (w << 5) + sRow) * K + sCol;
  const ushort* gA1 = gA0 + (size_t)16 * K;
  const ushort* gB0 = V + ub + (size_t)(col0 + (w << 5) + sRow) * K + sCol;
  const ushort* gB1 = gB0 + (size_t)16 * K;
  ushort* lA0 = &As[w << 5][0];
  ushort* lA1 = &As[(w << 5) + 16][0];
  ushort* lB0 = &Bs[w << 5][0];
  ushort* lB1 = &Bs[(w << 5) + 16][0];

  f32x4 acc[4][4];
#pragma unroll
  for (int i = 0; i < 4; ++i)
#pragma unroll
    for (int jx = 0; jx < 4; ++jx)
#pragma unroll
      for (int e = 0; e < 4; ++e) acc[i][jx][e] = 0.f;

  for (int k0 = 0; k0 < K; k0 += 32) {
    gload16(gA0 + k0, lA0);
    gload16(gA1 + k0, lA1);
    gload16(gB0 + k0, lB0);
    gload16(gB1 + k0, lB1);
    __syncthreads();
    bf16x8 af[4], bfv[4];
#pragma unroll
    for (int fr = 0; fr < 4; ++fr) {
      const int r = (wr << 6) + (fr << 4) + l15;
      af[fr] = *(const bf16x8*)&As[r][(slot ^ ((r >> 1) & 3)) << 3];
    }
#pragma unroll
    for (int fc = 0; fc < 4; ++fc) {
      const int r = (wc << 6) + (fc << 4) + l15;
      bfv[fc] = *(const bf16x8*)&Bs[r][(slot ^ ((r >> 1) & 3)) << 3];
    }
#pragma unroll
    for (int fr = 0; fr < 4; ++fr)
#pragma unroll
      for (int fc = 0; fc < 4; ++fc)
        acc[fr][fc] = __builtin_amdgcn_mfma_f32_16x16x32_bf16(af[fr], bfv[fc], acc[fr][fc], 0, 0, 0);
    __syncthreads();
  }

  // Epilogue. C/D layout (m89-verified): col = lane&15, row = (lane>>4)*4 + reg.
  if constexpr (MODE == 2) {
    float colp[4] = {0.f, 0.f, 0.f, 0.f};
#pragma unroll
    for (int fr = 0; fr < 4; ++fr) {
#pragma unroll
      for (int jx = 0; jx < 4; ++jx) {
        const int grow = row0 + (wr << 6) + (fr << 4) + (slot << 2) + jx;
        float rs = 0.f;
#pragma unroll
        for (int fc = 0; fc < 4; ++fc) {
          const float e = expf(acc[fr][fc][jx] * INV_T);
          rs += e;
          colp[fc] += e;
        }
#pragma unroll
        for (int o = 1; o < 16; o <<= 1) rs += __shfl_xor(rs, o);
        if (l15 == 0) atomicAdd(&denR[(size_t)b * NN_ + grow], rs);
      }
    }
#pragma unroll
    for (int fc = 0; fc < 4; ++fc) {
      float cs = colp[fc];
      cs += __shfl_xor(cs, 16);
      cs += __shfl_xor(cs, 32);
      if (slot == 0) atomicAdd(&denC[(size_t)b * NN_ + col0 + (wc << 6) + (fc << 4) + l15], cs);
    }
  } else if constexpr (MODE == 4) {
    __shared__ ushort tb[128][136];  // C^T bounce tile, padded stride
#pragma unroll
    for (int fr = 0; fr < 4; ++fr) {
#pragma unroll
      for (int jx = 0; jx < 4; ++jx) {
        const int lrow = (wr << 6) + (fr << 4) + (slot << 2) + jx;
        const int grow = row0 + lrow;
#pragma unroll
        for (int fc = 0; fc < 4; ++fc) {
          const int lcol = (wc << 6) + (fc << 4) + l15;
          const ushort h = f2b(acc[fr][fc][jx]);
          C[cb + (size_t)grow * NN_ + col0 + lcol] = h;
          tb[lcol][lrow] = h;
        }
      }
    }
    __syncthreads();
#pragma unroll
    for (int rep = 0; rep < 8; ++rep) {
      const int cid = rep * 256 + t;   // 0..2047
      const int r = cid >> 4;          // 0..127 (C^T row = local col)
      const int c8 = (cid & 15) << 3;  // 0..120
      *(uint4*)&Ct[cb + (size_t)(col0 + r) * NN_ + row0 + c8] = *(const uint4*)&tb[r][c8];
    }
  } else {  // MODE 1
#pragma unroll
    for (int fr = 0; fr < 4; ++fr) {
#pragma unroll
      for (int jx = 0; jx < 4; ++jx) {
        const int grow = row0 + (wr << 6) + (fr << 4) + (slot << 2) + jx;
        float rs = 0.f;
#pragma unroll
        for (int fc = 0; fc < 4; ++fc) {
          const int gcol = col0 + (wc << 6) + (fc << 4) + l15;
          const float v = acc[fr][fc][jx];
          C[cb + (size_t)grow * NN_ + gcol] = f2b(v);
          if (grow != gcol) rs += expf(v * INV_T);
        }
#pragma unroll
        for (int o = 1; o < 16; o <<= 1) rs += __shfl_xor(rs, o);
        if (l15 == 0) atomicAdd(&denR[(size_t)b * NN_ + grow], rs);
      }
    }
  }
}

// ---------------- in-place row softmax on bf16 matrix ----------------
__global__ __launch_bounds__(256) void k_softmax(ushort* __restrict__ S) {
  const size_t row = blockIdx.x;
  const int t = threadIdx.x;
  ushort* sr = S + row * (size_t)NN_;
  ushort4 u = *(const ushort4*)&sr[t << 2];
  float v0 = b2f(u.x), v1 = b2f(u.y), v2 = b2f(u.z), v3 = b2f(u.w);
  float m = fmaxf(fmaxf(v0, v1), fmaxf(v2, v3));
#pragma unroll
  for (int o = 32; o; o >>= 1) m = fmaxf(m, __shfl_xor(m, o));
  __shared__ float pm[4], ps[4];
  if ((t & 63) == 0) pm[t >> 6] = m;
  __syncthreads();
  m = fmaxf(fmaxf(pm[0], pm[1]), fmaxf(pm[2], pm[3]));
  const float e0 = expf(v0 - m), e1 = expf(v1 - m), e2 = expf(v2 - m), e3 = expf(v3 - m);
  float s = e0 + e1 + e2 + e3;
#pragma unroll
  for (int o = 32; o; o >>= 1) s += __shfl_xor(s, o);
  if ((t & 63) == 0) ps[t >> 6] = s;
  __syncthreads();
  s = ps[0] + ps[1] + ps[2] + ps[3];
  const float inv = 1.0f / s;
  ushort4 wq;
  wq.x = f2b(e0 * inv); wq.y = f2b(e1 * inv); wq.z = f2b(e2 * inv); wq.w = f2b(e3 * inv);
  *(ushort4*)&sr[t << 2] = wq;
}

// ---------------- bf16 NxN transpose (per batch), 64x64 tiles ----------------
__global__ __launch_bounds__(256) void k_transpose(const ushort* __restrict__ in, ushort* __restrict__ out) {
  const int b = blockIdx.z;
  const size_t mb = (size_t)b * NN_ * NN_;
  const int bx = blockIdx.x, by = blockIdx.y;
  __shared__ ushort tl[64][65];
  const int t = threadIdx.x;
  const int r = t >> 3, c = (t & 7) << 3;
#pragma unroll
  for (int h = 0; h < 2; ++h) {
    const int rr = r + h * 32;
    uint4 v = *(const uint4*)&in[mb + (size_t)(by * 64 + rr) * NN_ + bx * 64 + c];
    const ushort* pv = (const ushort*)&v;
#pragma unroll
    for (int e = 0; e < 8; ++e) tl[rr][c + e] = pv[e];
  }
  __syncthreads();
#pragma unroll
  for (int h = 0; h < 2; ++h) {
    const int rr = r + h * 32;
    ushort tmp[8];
#pragma unroll
    for (int e = 0; e < 8; ++e) tmp[e] = tl[c + e][rr];
    *(uint4*)&out[mb + (size_t)(bx * 64 + rr) * NN_ + by * 64 + c] = *(const uint4*)tmp;
  }
}

// ---------------- banded loss: top-5 is provably the 5 nearest indices ----------------
// pw 5th-vs-6th gap >= 0.0458; assoc contribution <= 3.6e-3 (row-stochastic A bounds) -> set is fixed.
// scores needed only at window [clamp(i-2,0,N-5), +4]; A,A2 band read directly, A4 band = dot(A2[i,:],A2t[j,:]).
__global__ __launch_bounds__(256) void k_loss(const ushort* __restrict__ A, const ushort* __restrict__ A2,
                                              const ushort* __restrict__ A2t, const ushort* __restrict__ znS,
                                              const ushort* __restrict__ znO, const float* __restrict__ den,
                                              float* __restrict__ lossRows, int halfOff) {
  const int row = (blockIdx.x << 2) + (threadIdx.x >> 6);  // 0..BB*NN_-1, one wave per row
  const int lane = threadIdx.x & 63;
  const int b = row >> 10, i = row & 1023;
  const size_t mb = (size_t)b * NN_ * NN_;
  const int w0 = min(max(i - 2, 0), NN_ - 5);

  // A^2 row i fragment: 16 elems per lane
  const ushort* zr = A2 + mb + (size_t)i * NN_ + (lane << 4);
  const bf16x8 r0 = *(const bf16x8*)zr;
  const bf16x8 r1 = *(const bf16x8*)(zr + 8);

  // znS row i fragment: 4 elems per lane
  const ushort4 qv = *(const ushort4*)&znS[((size_t)b * NN_ + i) * DD + (lane << 2)];
  const float q0 = b2f(qv.x), q1 = b2f(qv.y), q2 = b2f(qv.z), q3 = b2f(qv.w);

  float a4[5], cd[5];
#pragma unroll
  for (int s = 0; s < 5; ++s) {
    const int j = w0 + s;
    float p = 0.f;
    if (j != i) {  // wave-uniform branch
      const ushort* wrp = A2t + mb + (size_t)j * NN_ + (lane << 4);
      const bf16x8 wv0 = *(const bf16x8*)wrp;
      const bf16x8 wv1 = *(const bf16x8*)(wrp + 8);
#pragma unroll
      for (int e = 0; e < 8; ++e)
        p += b2f((ushort)r0[e]) * b2f((ushort)wv0[e]) + b2f((ushort)r1[e]) * b2f((ushort)wv1[e]);
    }
    const ushort4 ov = *(const ushort4*)&znO[((size_t)b * NN_ + j) * DD + (lane << 2)];
    float c = q0 * b2f(ov.x) + q1 * b2f(ov.y) + q2 * b2f(ov.z) + q3 * b2f(ov.w);
#pragma unroll
    for (int o = 32; o; o >>= 1) { p += __shfl_xor(p, o); c += __shfl_xor(c, o); }
    a4[s] = p;
    cd[s] = c;
  }

  float num = 0.f;
#pragma unroll
  for (int s = 0; s < 5; ++s) {
    const int j = w0 + s;
    const float g = expf(cd[s] * INV_T);
    if (j == i) {
      num += g;  // strong term
    } else {
      const float d = (float)(j - i);
      const float pw = expf(-d * d * 0.125f);
      const float aband = b2f(A[mb + (size_t)i * NN_ + j]);
      const float a2band = b2f(A2[mb + (size_t)i * NN_ + j]);
      const float sc = 0.5f * pw + (aband + a2band + a4[s]) * (0.5f / 3.0f);
      num += sc * g;
    }
  }

  if (lane == 0) {
    const float dn = den[(size_t)b * NN_ + i];
    lossRows[(size_t)b * (2 * NN_) + halfOff + i] = -logf(num / (dn + 1e-9f) + 1e-9f);
  }
}

// ---------------- final mean ----------------
__global__ __launch_bounds__(256) void k_final(const float* __restrict__ lossRows, float* __restrict__ out) {
  const int t = threadIdx.x;
  float s = 0.f;
  for (int idx = t; idx < BB * 2 * NN_; idx += 256) s += lossRows[idx];
#pragma unroll
  for (int o = 32; o; o >>= 1) s += __shfl_xor(s, o);
  __shared__ float p[4];
  if ((t & 63) == 0) p[t >> 6] = s;
  __syncthreads();
  if (t == 0) out[0] = (p[0] + p[1] + p[2] + p[3]) / (float)(BB * 2 * NN_);
}

extern "C" void kernel_launch(void* const* d_in, const int* in_sizes, int n_in, void* d_out, int out_size,
                              void* d_ws, size_t ws_size, hipStream_t stream) {
  const float* z1 = (const float*)d_in[0];
  const float* z2 = (const float*)d_in[1];
  float* out = (float*)d_out;

  const size_t nzd = (size_t)BB * NN_ * DD;
  const size_t nnn = (size_t)BB * NN_ * NN_;

  ushort* zn1 = (ushort*)d_ws;
  ushort* zn2 = zn1 + nzd;
  ushort* X = zn2 + nzd;
  ushort* Y = X + nnn;
  ushort* Z = Y + nnn;
  float* den1 = (float*)(Z + nnn);
  float* den2 = den1 + (size_t)BB * NN_;
  float* lossRows = den2 + (size_t)BB * NN_;
  ushort* W = (ushort*)(lossRows + 2 * (size_t)BB * NN_);

  const size_t needed = 2 * nzd * 2 + 4 * nnn * 2 + 4 * (size_t)BB * NN_ * 4;
  if (ws_size < needed) return;  // fail cleanly instead of faulting (round-5 proved this fits)

  dim3 blk(256);
  const int gFlat = (NN_ / 128) * (NN_ / 128) * BB;  // 1024
  dim3 gT(NN_ / 64, NN_ / 64, BB);
  const int gLoss = (BB * NN_) / 4;  // 4096 blocks, one wave per row

  hipMemsetAsync(den1, 0, 2 * (size_t)BB * NN_ * 4, stream);

  k_norm<<<2 * BB * NN_, blk, 0, stream>>>(z1, z2, zn1);

  // half 2: X = S22 (+den2 same-half part), softmax -> A2
  k_gemm_nt<1, DD><<<gFlat, blk, 0, stream>>>(zn2, zn2, X, den2, nullptr, nullptr);
  k_softmax<<<BB * NN_, blk, 0, stream>>>(X);                                     // X = A2
  k_transpose<<<gT, blk, 0, stream>>>(X, Y);                                      // Y = A2^T
  k_gemm_nt<4, NN_><<<gFlat, blk, 0, stream>>>(X, Y, Z, nullptr, nullptr, W);     // Z = A2^2, W = (A2^2)^T

  // cross den contributions (S21 = S12^T)
  k_gemm_nt<2, DD><<<gFlat, blk, 0, stream>>>(zn1, zn2, nullptr, den1, den2, nullptr);

  // half 1: Y = S11 (+den1 same-half part), softmax -> A1   (A2^T no longer needed)
  k_gemm_nt<1, DD><<<gFlat, blk, 0, stream>>>(zn1, zn1, Y, den1, nullptr, nullptr);
  k_softmax<<<BB * NN_, blk, 0, stream>>>(Y);                                     // Y = A1

  // loss rows for half 1 (uses A2 family + den1)
  k_loss<<<gLoss, blk, 0, stream>>>(X, Z, W, zn1, zn2, den1, lossRows, 0);

  k_transpose<<<gT, blk, 0, stream>>>(Y, X);                                      // X = A1^T (A2 dead)
  k_gemm_nt<4, NN_><<<gFlat, blk, 0, stream>>>(Y, X, Z, nullptr, nullptr, W);     // Z = A1^2, W = (A1^2)^T

  // loss rows for half 2 (uses A1 family + den2)
  k_loss<<<gLoss, blk, 0, stream>>>(Y, Z, W, zn2, zn1, den2, lossRows, NN_);

  k_final<<<1, blk, 0, stream>>>(lossRows, out);
}

// Round 7
// 363.169 us; speedup vs baseline: 2.4914x; 1.1180x over previous
//
#include <hip/hip_runtime.h>
#include <cmath>
#include <cstdint>

#define BB 16
#define NN_ 1024
#define DD 256

constexpr float INV_T = 1.0f / 0.07f;

typedef __attribute__((ext_vector_type(8))) short bf16x8;
typedef __attribute__((ext_vector_type(4))) float f32x4;

static __device__ __forceinline__ float b2f(ushort u) {
  union { uint i; float f; } c; c.i = ((uint)u) << 16; return c.f;
}
static __device__ __forceinline__ ushort f2b(float f) {
  union { float f; uint i; } c; c.f = f;
  uint r = c.i + 0x7fffu + ((c.i >> 16) & 1u);
  return (ushort)(r >> 16);
}

// async global->LDS, 16B per lane, LDS dest = wave-uniform base + lane*16
static __device__ __forceinline__ void gload16(const void* g, void* l) {
  __builtin_amdgcn_global_load_lds((const __attribute__((address_space(1))) unsigned int*)g,
                                   (__attribute__((address_space(3))) unsigned int*)l, 16, 0, 0);
}

// ---------------- row normalize: z(f32) -> zn(bf16), both halves in one launch ----------------
__global__ __launch_bounds__(256) void k_norm(const float* __restrict__ z1, const float* __restrict__ z2,
                                              ushort* __restrict__ znAll) {
  const int row = blockIdx.x;  // 0 .. 2*BB*NN_-1
  const int t = threadIdx.x;
  const bool second = row >= BB * NN_;
  const float* z = second ? z2 : z1;
  const size_t inBase = (size_t)(second ? row - BB * NN_ : row) * DD + t;
  float v = z[inBase];
  float ss = v * v;
#pragma unroll
  for (int o = 32; o; o >>= 1) ss += __shfl_xor(ss, o);
  __shared__ float par[4];
  if ((t & 63) == 0) par[t >> 6] = ss;
  __syncthreads();
  float tot = par[0] + par[1] + par[2] + par[3];
  znAll[(size_t)row * DD + t] = f2b(v / (sqrtf(tot) + 1e-12f));
}

// ---------------- MFMA NT GEMM, double-buffered global_load_lds (1 barrier / K-step) -------------
// C = U * V^T, U:[N][K], V:[N][K] bf16. Flat 1024-block grid, XCD-batch-affinity decode.
// MODE 0 (SQ):        store bf16 acc  (used as M^2 = M * M^T with U==V==M symmetric)
// MODE 1 (SIM_SAME):  store bf16 exp(acc); denR[row] += sum_col exp(acc*INV_T) skip diag;
//                     rsum[row] += sum_col exp(acc)  (softmax row sums, diag included)
// MODE 2 (SIM_CROSS): no store; denR += row-sums of exp(/T), denC += col-sums (S21 = S12^T)
template <int MODE, int K>
__global__ __launch_bounds__(256) void k_gemm_nt(const ushort* __restrict__ U, const ushort* __restrict__ V,
                                                 ushort* __restrict__ C, float* __restrict__ denR,
                                                 float* __restrict__ denC, float* __restrict__ rsum) {
  __shared__ __align__(16) ushort As[2][128][32];
  __shared__ __align__(16) ushort Bs[2][128][32];
  const int t = threadIdx.x;
  // --- XCD-affinity decode: block i -> XCD i&7, each XCD owns 2 whole batches ---
  const int fid = blockIdx.x;
  const int xcd = fid & 7, j = fid >> 3;
  const int b = (xcd << 1) | (j >> 6);
  const int jj = j & 63;
  const int row0 = (jj >> 3) << 7, col0 = (jj & 7) << 7;

  const size_t ub = (size_t)b * NN_ * K;
  const size_t cb = (size_t)b * NN_ * NN_;
  const int lane = t & 63, w = t >> 6;
  const int wr = w >> 1, wc = w & 1;
  const int l15 = lane & 15, slot = lane >> 4;

  // staging: wave w owns rows w*32..w*32+31 of both tiles
  const int sRow = lane >> 2;                     // 0..15
  const int kg = (lane & 3) ^ ((lane >> 3) & 3);  // swizzled k-group (source side, m173 pattern)
  const int sCol = kg << 3;
  const ushort* gA0 = U + ub + (size_t)(row0 + (w << 5) + sRow) * K + sCol;
  const ushort* gA1 = gA0 + (size_t)16 * K;
  const ushort* gB0 = V + ub + (size_t)(col0 + (w << 5) + sRow) * K + sCol;
  const ushort* gB1 = gB0 + (size_t)16 * K;

  f32x4 acc[4][4];
#pragma unroll
  for (int i = 0; i < 4; ++i)
#pragma unroll
    for (int jx = 0; jx < 4; ++jx)
#pragma unroll
      for (int e = 0; e < 4; ++e) acc[i][jx][e] = 0.f;

  // prologue: stage tile 0 into buffer 0; __syncthreads drains vmcnt
  gload16(gA0, &As[0][w << 5][0]);
  gload16(gA1, &As[0][(w << 5) + 16][0]);
  gload16(gB0, &Bs[0][w << 5][0]);
  gload16(gB1, &Bs[0][(w << 5) + 16][0]);
  __syncthreads();

  int cur = 0;
  for (int k0 = 0; k0 < K; k0 += 32) {
    const int nxt = cur ^ 1;
    if (k0 + 32 < K) {  // issue next-tile stage early; latency hides under MFMA below
      gload16(gA0 + k0 + 32, &As[nxt][w << 5][0]);
      gload16(gA1 + k0 + 32, &As[nxt][(w << 5) + 16][0]);
      gload16(gB0 + k0 + 32, &Bs[nxt][w << 5][0]);
      gload16(gB1 + k0 + 32, &Bs[nxt][(w << 5) + 16][0]);
    }
    bf16x8 af[4], bfv[4];
#pragma unroll
    for (int fr = 0; fr < 4; ++fr) {
      const int r = (wr << 6) + (fr << 4) + l15;
      af[fr] = *(const bf16x8*)&As[cur][r][(slot ^ ((r >> 1) & 3)) << 3];
    }
#pragma unroll
    for (int fc = 0; fc < 4; ++fc) {
      const int r = (wc << 6) + (fc << 4) + l15;
      bfv[fc] = *(const bf16x8*)&Bs[cur][r][(slot ^ ((r >> 1) & 3)) << 3];
    }
#pragma unroll
    for (int fr = 0; fr < 4; ++fr)
#pragma unroll
      for (int fc = 0; fc < 4; ++fc)
        acc[fr][fc] = __builtin_amdgcn_mfma_f32_16x16x32_bf16(af[fr], bfv[fc], acc[fr][fc], 0, 0, 0);
    __syncthreads();  // drains vmcnt (stage done) + lgkmcnt (reads done) for safe rotation
    cur = nxt;
  }

  // Epilogue. C/D layout (m89-verified): col = lane&15, row = (lane>>4)*4 + reg.
  if constexpr (MODE == 2) {
    float colp[4] = {0.f, 0.f, 0.f, 0.f};
#pragma unroll
    for (int fr = 0; fr < 4; ++fr) {
#pragma unroll
      for (int jx = 0; jx < 4; ++jx) {
        const int grow = row0 + (wr << 6) + (fr << 4) + (slot << 2) + jx;
        float rs = 0.f;
#pragma unroll
        for (int fc = 0; fc < 4; ++fc) {
          const float e = expf(acc[fr][fc][jx] * INV_T);
          rs += e;
          colp[fc] += e;
        }
#pragma unroll
        for (int o = 1; o < 16; o <<= 1) rs += __shfl_xor(rs, o);
        if (l15 == 0) atomicAdd(&denR[(size_t)b * NN_ + grow], rs);
      }
    }
#pragma unroll
    for (int fc = 0; fc < 4; ++fc) {
      float cs = colp[fc];
      cs += __shfl_xor(cs, 16);
      cs += __shfl_xor(cs, 32);
      if (slot == 0) atomicAdd(&denC[(size_t)b * NN_ + col0 + (wc << 6) + (fc << 4) + l15], cs);
    }
  } else if constexpr (MODE == 1) {
#pragma unroll
    for (int fr = 0; fr < 4; ++fr) {
#pragma unroll
      for (int jx = 0; jx < 4; ++jx) {
        const int grow = row0 + (wr << 6) + (fr << 4) + (slot << 2) + jx;
        float rs = 0.f, es = 0.f;
#pragma unroll
        for (int fc = 0; fc < 4; ++fc) {
          const int gcol = col0 + (wc << 6) + (fc << 4) + l15;
          const float v = acc[fr][fc][jx];
          const float ev = expf(v);
          C[cb + (size_t)grow * NN_ + gcol] = f2b(ev);  // E = exp(S), symmetric, in [e^-1, e]
          es += ev;
          if (grow != gcol) rs += expf(v * INV_T);
        }
#pragma unroll
        for (int o = 1; o < 16; o <<= 1) { rs += __shfl_xor(rs, o); es += __shfl_xor(es, o); }
        if (l15 == 0) {
          atomicAdd(&denR[(size_t)b * NN_ + grow], rs);
          atomicAdd(&rsum[(size_t)b * NN_ + grow], es);
        }
      }
    }
  } else {  // MODE 0
#pragma unroll
    for (int fr = 0; fr < 4; ++fr) {
#pragma unroll
      for (int jx = 0; jx < 4; ++jx) {
        const int grow = row0 + (wr << 6) + (fr << 4) + (slot << 2) + jx;
#pragma unroll
        for (int fc = 0; fc < 4; ++fc) {
          const int gcol = col0 + (wc << 6) + (fc << 4) + l15;
          C[cb + (size_t)grow * NN_ + gcol] = f2b(acc[fr][fc][jx]);
        }
      }
    }
  }
}

// ---------------- scale: M = E * rsqrt(r_i) * rsqrt(r_j), in place (reduction-free) ----------------
__global__ __launch_bounds__(256) void k_scale(ushort* __restrict__ E, const float* __restrict__ r) {
  const size_t idx8 = ((size_t)blockIdx.x * 256 + threadIdx.x) << 3;  // 8 elems/thread
  const int grow = (int)(idx8 >> 10);     // global row b*NN_+i
  const int bcol = (int)(idx8 & 1023);
  const int batch = grow >> 10;
  const float rsi = rsqrtf(r[grow]);
  bf16x8 v = *(const bf16x8*)&E[idx8];
  const float* rb = r + (batch << 10) + bcol;
  const float4 rc0 = *(const float4*)rb;
  const float4 rc1 = *(const float4*)(rb + 4);
  float rj[8] = {rc0.x, rc0.y, rc0.z, rc0.w, rc1.x, rc1.y, rc1.z, rc1.w};
  bf16x8 o;
#pragma unroll
  for (int e = 0; e < 8; ++e) {
    const float wgt = rsi * rsqrtf(rj[e]);  // commutative product -> M bit-symmetric
    o[e] = (short)f2b(b2f((ushort)v[e]) * wgt);
  }
  *(bf16x8*)&E[idx8] = o;
}

// ---------------- banded loss (top-5 provably the 5 nearest indices) ----------------
// assoc_band(i,j) = sqrt(r_j/r_i) * (M + M^2 + M^4)[i,j];  M^4 band = dot(M2[i,:], M2[j,:]) (M2 symmetric).
__global__ __launch_bounds__(256) void k_loss(const ushort* __restrict__ M, const ushort* __restrict__ M2,
                                              const float* __restrict__ r, const ushort* __restrict__ znS,
                                              const ushort* __restrict__ znO, const float* __restrict__ den,
                                              float* __restrict__ lossRows, int halfOff) {
  const int row = (blockIdx.x << 2) + (threadIdx.x >> 6);  // one wave per row
  const int lane = threadIdx.x & 63;
  const int b = row >> 10, i = row & 1023;
  const size_t mb = (size_t)b * NN_ * NN_;
  const int w0 = min(max(i - 2, 0), NN_ - 5);

  // M2 row i fragment: 16 elems per lane
  const ushort* zr = M2 + mb + (size_t)i * NN_ + (lane << 4);
  const bf16x8 r0 = *(const bf16x8*)zr;
  const bf16x8 r1 = *(const bf16x8*)(zr + 8);

  const ushort4 qv = *(const ushort4*)&znS[((size_t)b * NN_ + i) * DD + (lane << 2)];
  const float q0 = b2f(qv.x), q1 = b2f(qv.y), q2 = b2f(qv.z), q3 = b2f(qv.w);

  float a4[5], cd[5];
#pragma unroll
  for (int s = 0; s < 5; ++s) {
    const int j = w0 + s;
    float p = 0.f;
    if (j != i) {  // wave-uniform branch
      const ushort* wrp = M2 + mb + (size_t)j * NN_ + (lane << 4);
      const bf16x8 wv0 = *(const bf16x8*)wrp;
      const bf16x8 wv1 = *(const bf16x8*)(wrp + 8);
#pragma unroll
      for (int e = 0; e < 8; ++e)
        p += b2f((ushort)r0[e]) * b2f((ushort)wv0[e]) + b2f((ushort)r1[e]) * b2f((ushort)wv1[e]);
    }
    const ushort4 ov = *(const ushort4*)&znO[((size_t)b * NN_ + j) * DD + (lane << 2)];
    float c = q0 * b2f(ov.x) + q1 * b2f(ov.y) + q2 * b2f(ov.z) + q3 * b2f(ov.w);
#pragma unroll
    for (int o = 32; o; o >>= 1) { p += __shfl_xor(p, o); c += __shfl_xor(c, o); }
    a4[s] = p;
    cd[s] = c;
  }

  const float rsi = rsqrtf(r[(size_t)b * NN_ + i]);
  float num = 0.f;
#pragma unroll
  for (int s = 0; s < 5; ++s) {
    const int j = w0 + s;
    const float g = expf(cd[s] * INV_T);
    if (j == i) {
      num += g;  // strong term
    } else {
      const float d = (float)(j - i);
      const float pw = expf(-d * d * 0.125f);
      const float ratio = sqrtf(r[(size_t)b * NN_ + j]) * rsi;  // sqrt(r_j / r_i)
      const float mband = b2f(M[mb + (size_t)i * NN_ + j]);
      const float m2band = b2f(M2[mb + (size_t)i * NN_ + j]);
      const float sc = 0.5f * pw + ratio * (mband + m2band + a4[s]) * (0.5f / 3.0f);
      num += sc * g;
    }
  }

  if (lane == 0) {
    const float dn = den[(size_t)b * NN_ + i];
    lossRows[(size_t)b * (2 * NN_) + halfOff + i] = -logf(num / (dn + 1e-9f) + 1e-9f);
  }
}

// ---------------- final mean ----------------
__global__ __launch_bounds__(256) void k_final(const float* __restrict__ lossRows, float* __restrict__ out) {
  const int t = threadIdx.x;
  float s = 0.f;
  for (int idx = t; idx < BB * 2 * NN_; idx += 256) s += lossRows[idx];
#pragma unroll
  for (int o = 32; o; o >>= 1) s += __shfl_xor(s, o);
  __shared__ float p[4];
  if ((t & 63) == 0) p[t >> 6] = s;
  __syncthreads();
  if (t == 0) out[0] = (p[0] + p[1] + p[2] + p[3]) / (float)(BB * 2 * NN_);
}

extern "C" void kernel_launch(void* const* d_in, const int* in_sizes, int n_in, void* d_out, int out_size,
                              void* d_ws, size_t ws_size, hipStream_t stream) {
  const float* z1 = (const float*)d_in[0];
  const float* z2 = (const float*)d_in[1];
  float* out = (float*)d_out;

  const size_t nzd = (size_t)BB * NN_ * DD;
  const size_t nnn = (size_t)BB * NN_ * NN_;
  const size_t nv = (size_t)BB * NN_;

  ushort* zn1 = (ushort*)d_ws;
  ushort* zn2 = zn1 + nzd;
  ushort* X = zn2 + nzd;   // E2 -> M(half2)
  ushort* Y = X + nnn;     // E1 -> M(half1)
  ushort* Z = Y + nnn;     // M2^2 then M1^2
  float* den1 = (float*)(Z + nnn);
  float* den2 = den1 + nv;
  float* rsum1 = den2 + nv;
  float* rsum2 = rsum1 + nv;
  float* lossRows = rsum2 + nv;

  const size_t needed = 2 * nzd * 2 + 3 * nnn * 2 + 6 * nv * 4;
  if (ws_size < needed) return;  // fail cleanly instead of faulting

  dim3 blk(256);
  const int gFlat = (NN_ / 128) * (NN_ / 128) * BB;  // 1024
  const int gScale = (int)(nnn / 2048);              // 8192
  const int gLoss = (int)(nv / 4);                   // 4096

  hipMemsetAsync(den1, 0, 4 * nv * 4, stream);  // den1, den2, rsum1, rsum2

  k_norm<<<2 * BB * NN_, blk, 0, stream>>>(z1, z2, zn1);

  // half 2: X = E2 = exp(S22), den2 same-half part, rsum2
  k_gemm_nt<1, DD><<<gFlat, blk, 0, stream>>>(zn2, zn2, X, den2, nullptr, rsum2);
  k_scale<<<gScale, blk, 0, stream>>>(X, rsum2);                              // X = M(h2)
  k_gemm_nt<0, NN_><<<gFlat, blk, 0, stream>>>(X, X, Z, nullptr, nullptr, nullptr);  // Z = M2^2

  // cross den contributions (S21 = S12^T)
  k_gemm_nt<2, DD><<<gFlat, blk, 0, stream>>>(zn1, zn2, nullptr, den1, den2, nullptr);

  // half 1: Y = E1 = exp(S11), den1 same-half part, rsum1
  k_gemm_nt<1, DD><<<gFlat, blk, 0, stream>>>(zn1, zn1, Y, den1, nullptr, rsum1);
  k_scale<<<gScale, blk, 0, stream>>>(Y, rsum1);                              // Y = M(h1)

  // loss rows half 1 (assoc of half 2: X, Z, rsum2; den1)
  k_loss<<<gLoss, blk, 0, stream>>>(X, Z, rsum2, zn1, zn2, den1, lossRows, 0);

  k_gemm_nt<0, NN_><<<gFlat, blk, 0, stream>>>(Y, Y, Z, nullptr, nullptr, nullptr);  // Z = M1^2

  // loss rows half 2 (assoc of half 1: Y, Z, rsum1; den2)
  k_loss<<<gLoss, blk, 0, stream>>>(Y, Z, rsum1, zn2, zn1, den2, lossRows, NN_);

  k_final<<<1, blk, 0, stream>>>(lossRows, out);
}

// Round 9
// 326.526 us; speedup vs baseline: 2.7710x; 1.1122x over previous
//
#include <hip/hip_runtime.h>
#include <cmath>
#include <cstdint>

#define BB 16
#define NN_ 1024
#define DD 256

constexpr float INV_T = 1.0f / 0.07f;

typedef __attribute__((ext_vector_type(8))) short bf16x8;
typedef __attribute__((ext_vector_type(4))) float f32x4;

static __device__ __forceinline__ float b2f(ushort u) {
  union { uint i; float f; } c; c.i = ((uint)u) << 16; return c.f;
}
static __device__ __forceinline__ ushort f2b(float f) {
  union { float f; uint i; } c; c.f = f;
  uint r = c.i + 0x7fffu + ((c.i >> 16) & 1u);
  return (ushort)(r >> 16);
}

// async global->LDS, 16B per lane, LDS dest = wave-uniform base + lane*16
static __device__ __forceinline__ void gload16(const void* g, void* l) {
  __builtin_amdgcn_global_load_lds((const __attribute__((address_space(1))) unsigned int*)g,
                                   (__attribute__((address_space(3))) unsigned int*)l, 16, 0, 0);
}

// ---------------- row normalize: z(f32) -> zn(bf16), both halves in one launch ----------------
__global__ __launch_bounds__(256) void k_norm(const float* __restrict__ z1, const float* __restrict__ z2,
                                              ushort* __restrict__ znAll) {
  const int row = blockIdx.x;  // 0 .. 2*BB*NN_-1
  const int t = threadIdx.x;
  const bool second = row >= BB * NN_;
  const float* z = second ? z2 : z1;
  const size_t inBase = (size_t)(second ? row - BB * NN_ : row) * DD + t;
  float v = z[inBase];
  float ss = v * v;
#pragma unroll
  for (int o = 32; o; o >>= 1) ss += __shfl_xor(ss, o);
  __shared__ float par[4];
  if ((t & 63) == 0) par[t >> 6] = ss;
  __syncthreads();
  float tot = par[0] + par[1] + par[2] + par[3];
  znAll[(size_t)row * DD + t] = f2b(v / (sqrtf(tot) + 1e-12f));
}

// ---------------- MFMA NT GEMM, double-buffered global_load_lds, 1 barrier / K-step -------------
// C = U * V^T, U:[N][K], V:[N][K] bf16. XCD-batch-affinity decode.
// TRI=1: symmetric output -> compute only the 36 upper-triangle 128^2 tiles/batch, mirror
//        off-diagonal tiles via LDS-bounce transposed store; lower-triangle den/rsum
//        contributions recovered as column-sums (bit-identical by k-sum commutativity).
// MODE 0 (SQ):        store bf16 acc            (M^2 = M * M^T, M symmetric)
// MODE 1 (SIM_SAME):  store bf16 exp(acc); denR[row] += sum exp(acc/T) skip diag; rsum[row] += sum exp(acc)
// MODE 2 (SIM_CROSS): no store; denR += row-sums of exp(/T), denC += col-sums (S21 = S12^T)
template <int MODE, int K, int TRI>
__global__ __launch_bounds__(256) void k_gemm_nt(const ushort* __restrict__ U, const ushort* __restrict__ V,
                                                 ushort* __restrict__ C, float* __restrict__ denR,
                                                 float* __restrict__ denC, float* __restrict__ rsum) {
  __shared__ __align__(16) ushort smem[17408];                      // union {As,Bs | tb}
  ushort (*As)[128][32] = (ushort (*)[128][32])smem;                // [2][128][32]
  ushort (*Bs)[128][32] = (ushort (*)[128][32])(smem + 8192);       // [2][128][32]
  ushort (*tb)[136] = (ushort (*)[136])smem;                        // [128][136], post-loop only

  const int t = threadIdx.x;
  const int fid = blockIdx.x;
  const int xcd = fid & 7;
  int b, row0, col0;
  if constexpr (TRI) {
    int j = fid >> 3;                    // 0..71 per XCD; 36 tiles per batch
    const int half = (j >= 36) ? 1 : 0;
    b = (xcd << 1) | half;
    int rem = j - half * 36;             // 0..35 triangular index
    int r = 0;
#pragma unroll
    for (int q = 0; q < 7; ++q) {
      if (rem >= 8 - r) { rem -= 8 - r; ++r; }
    }
    row0 = r << 7;
    col0 = (r + rem) << 7;
  } else {
    const int j = fid >> 3;
    b = (xcd << 1) | (j >> 6);
    const int jj = j & 63;
    row0 = (jj >> 3) << 7;
    col0 = (jj & 7) << 7;
  }

  const size_t ub = (size_t)b * NN_ * K;
  const size_t cb = (size_t)b * NN_ * NN_;
  const int lane = t & 63, w = t >> 6;
  const int wr = w >> 1, wc = w & 1;
  const int l15 = lane & 15, slot = lane >> 4;

  // staging: wave w owns rows w*32..w*32+31 of both tiles
  const int sRow = lane >> 2;                     // 0..15
  const int kg = (lane & 3) ^ ((lane >> 3) & 3);  // swizzled k-group (source side, m173 pattern)
  const int sCol = kg << 3;
  const ushort* gA0 = U + ub + (size_t)(row0 + (w << 5) + sRow) * K + sCol;
  const ushort* gA1 = gA0 + (size_t)16 * K;
  const ushort* gB0 = V + ub + (size_t)(col0 + (w << 5) + sRow) * K + sCol;
  const ushort* gB1 = gB0 + (size_t)16 * K;

  f32x4 acc[4][4];
#pragma unroll
  for (int i = 0; i < 4; ++i)
#pragma unroll
    for (int jx = 0; jx < 4; ++jx)
#pragma unroll
      for (int e = 0; e < 4; ++e) acc[i][jx][e] = 0.f;

  // prologue: stage tile 0 into buffer 0
  gload16(gA0, &As[0][w << 5][0]);
  gload16(gA1, &As[0][(w << 5) + 16][0]);
  gload16(gB0, &Bs[0][w << 5][0]);
  gload16(gB1, &Bs[0][(w << 5) + 16][0]);
  __syncthreads();

  int cur = 0;
  for (int k0 = 0; k0 < K; k0 += 32) {
    const int nxt = cur ^ 1;
    if (k0 + 32 < K) {  // issue next-tile stage early; latency hides under MFMA below
      gload16(gA0 + k0 + 32, &As[nxt][w << 5][0]);
      gload16(gA1 + k0 + 32, &As[nxt][(w << 5) + 16][0]);
      gload16(gB0 + k0 + 32, &Bs[nxt][w << 5][0]);
      gload16(gB1 + k0 + 32, &Bs[nxt][(w << 5) + 16][0]);
    }
    bf16x8 af[4], bfv[4];
#pragma unroll
    for (int fr = 0; fr < 4; ++fr) {
      const int r = (wr << 6) + (fr << 4) + l15;
      af[fr] = *(const bf16x8*)&As[cur][r][(slot ^ ((r >> 1) & 3)) << 3];
    }
#pragma unroll
    for (int fc = 0; fc < 4; ++fc) {
      const int r = (wc << 6) + (fc << 4) + l15;
      bfv[fc] = *(const bf16x8*)&Bs[cur][r][(slot ^ ((r >> 1) & 3)) << 3];
    }
#pragma unroll
    for (int fr = 0; fr < 4; ++fr)
#pragma unroll
      for (int fc = 0; fc < 4; ++fc)
        acc[fr][fc] = __builtin_amdgcn_mfma_f32_16x16x32_bf16(af[fr], bfv[fc], acc[fr][fc], 0, 0, 0);
    __syncthreads();  // drains vmcnt (stage done) + lgkmcnt (reads done) for safe rotation
    cur = nxt;
  }
  // All waves past their LDS reads -> smem reusable as tb.

  // Epilogue. C/D layout (m89-verified): col = lane&15, row = (lane>>4)*4 + reg.
  if constexpr (MODE == 2) {
    float colp[4] = {0.f, 0.f, 0.f, 0.f};
#pragma unroll
    for (int fr = 0; fr < 4; ++fr) {
#pragma unroll
      for (int jx = 0; jx < 4; ++jx) {
        const int grow = row0 + (wr << 6) + (fr << 4) + (slot << 2) + jx;
        float rs = 0.f;
#pragma unroll
        for (int fc = 0; fc < 4; ++fc) {
          const float e = expf(acc[fr][fc][jx] * INV_T);
          rs += e;
          colp[fc] += e;
        }
#pragma unroll
        for (int o = 1; o < 16; o <<= 1) rs += __shfl_xor(rs, o);
        if (l15 == 0) atomicAdd(&denR[(size_t)b * NN_ + grow], rs);
      }
    }
#pragma unroll
    for (int fc = 0; fc < 4; ++fc) {
      float cs = colp[fc];
      cs += __shfl_xor(cs, 16);
      cs += __shfl_xor(cs, 32);
      if (slot == 0) atomicAdd(&denC[(size_t)b * NN_ + col0 + (wc << 6) + (fc << 4) + l15], cs);
    }
  } else if constexpr (MODE == 1) {
    float colp_d[4] = {0.f, 0.f, 0.f, 0.f};
    float colp_e[4] = {0.f, 0.f, 0.f, 0.f};
#pragma unroll
    for (int fr = 0; fr < 4; ++fr) {
#pragma unroll
      for (int jx = 0; jx < 4; ++jx) {
        const int lrow = (wr << 6) + (fr << 4) + (slot << 2) + jx;
        const int grow = row0 + lrow;
        float rs = 0.f, es = 0.f;
#pragma unroll
        for (int fc = 0; fc < 4; ++fc) {
          const int lcol = (wc << 6) + (fc << 4) + l15;
          const int gcol = col0 + lcol;
          const float v = acc[fr][fc][jx];
          const float ev = expf(v);
          const ushort h = f2b(ev);
          C[cb + (size_t)grow * NN_ + gcol] = h;
          tb[lcol][lrow] = h;
          es += ev;
          colp_e[fc] += ev;
          const float dv = expf(v * INV_T);
          if (grow != gcol) { rs += dv; colp_d[fc] += dv; }
        }
#pragma unroll
        for (int o = 1; o < 16; o <<= 1) { rs += __shfl_xor(rs, o); es += __shfl_xor(es, o); }
        if (l15 == 0) {
          atomicAdd(&denR[(size_t)b * NN_ + grow], rs);
          atomicAdd(&rsum[(size_t)b * NN_ + grow], es);
        }
      }
    }
    if (row0 != col0) {  // wave-uniform; lower-triangle contributions + mirrored store
#pragma unroll
      for (int fc = 0; fc < 4; ++fc) {
        float cd = colp_d[fc], ce = colp_e[fc];
        cd += __shfl_xor(cd, 16); cd += __shfl_xor(cd, 32);
        ce += __shfl_xor(ce, 16); ce += __shfl_xor(ce, 32);
        if (slot == 0) {
          const int gcol = col0 + (wc << 6) + (fc << 4) + l15;
          atomicAdd(&denR[(size_t)b * NN_ + gcol], cd);
          atomicAdd(&rsum[(size_t)b * NN_ + gcol], ce);
        }
      }
      __syncthreads();
#pragma unroll
      for (int rep = 0; rep < 8; ++rep) {
        const int cid = rep * 256 + t;
        const int rr = cid >> 4;
        const int c8 = (cid & 15) << 3;
        *(uint4*)&C[cb + (size_t)(col0 + rr) * NN_ + row0 + c8] = *(const uint4*)&tb[rr][c8];
      }
    }
  } else {  // MODE 0
#pragma unroll
    for (int fr = 0; fr < 4; ++fr) {
#pragma unroll
      for (int jx = 0; jx < 4; ++jx) {
        const int lrow = (wr << 6) + (fr << 4) + (slot << 2) + jx;
        const int grow = row0 + lrow;
#pragma unroll
        for (int fc = 0; fc < 4; ++fc) {
          const int lcol = (wc << 6) + (fc << 4) + l15;
          const ushort h = f2b(acc[fr][fc][jx]);
          C[cb + (size_t)grow * NN_ + col0 + lcol] = h;
          if constexpr (TRI) tb[lcol][lrow] = h;
        }
      }
    }
    if constexpr (TRI) {
      if (row0 != col0) {
        __syncthreads();
#pragma unroll
        for (int rep = 0; rep < 8; ++rep) {
          const int cid = rep * 256 + t;
          const int rr = cid >> 4;
          const int c8 = (cid & 15) << 3;
          *(uint4*)&C[cb + (size_t)(col0 + rr) * NN_ + row0 + c8] = *(const uint4*)&tb[rr][c8];
        }
      }
    }
  }
}

// ---------------- scale: M = E * rsqrt(r_i) * rsqrt(r_j), in place (reduction-free) ----------------
__global__ __launch_bounds__(256) void k_scale(ushort* __restrict__ E, const float* __restrict__ r) {
  const size_t idx8 = ((size_t)blockIdx.x * 256 + threadIdx.x) << 3;  // 8 elems/thread
  const int grow = (int)(idx8 >> 10);     // global row b*NN_+i
  const int bcol = (int)(idx8 & 1023);
  const int batch = grow >> 10;
  const float rsi = rsqrtf(r[grow]);
  bf16x8 v = *(const bf16x8*)&E[idx8];
  const float* rb = r + (batch << 10) + bcol;
  const float4 rc0 = *(const float4*)rb;
  const float4 rc1 = *(const float4*)(rb + 4);
  float rj[8] = {rc0.x, rc0.y, rc0.z, rc0.w, rc1.x, rc1.y, rc1.z, rc1.w};
  bf16x8 o;
#pragma unroll
  for (int e = 0; e < 8; ++e) {
    const float wgt = rsi * rsqrtf(rj[e]);  // commutative product -> M bit-symmetric
    o[e] = (short)f2b(b2f((ushort)v[e]) * wgt);
  }
  *(bf16x8*)&E[idx8] = o;
}

// ---------------- banded loss (top-5 provably the 5 nearest indices) ----------------
// assoc_band(i,j) = sqrt(r_j/r_i) * (M + M^2 + M^4)[i,j];  M^4 band = dot(M2[i,:], M2[j,:]) (M2 symmetric).
__global__ __launch_bounds__(256) void k_loss(const ushort* __restrict__ M, const ushort* __restrict__ M2,
                                              const float* __restrict__ r, const ushort* __restrict__ znS,
                                              const ushort* __restrict__ znO, const float* __restrict__ den,
                                              float* __restrict__ lossRows, int halfOff) {
  const int row = (blockIdx.x << 2) + (threadIdx.x >> 6);  // one wave per row
  const int lane = threadIdx.x & 63;
  const int b = row >> 10, i = row & 1023;
  const size_t mb = (size_t)b * NN_ * NN_;
  const int w0 = min(max(i - 2, 0), NN_ - 5);

  const ushort* zr = M2 + mb + (size_t)i * NN_ + (lane << 4);
  const bf16x8 r0 = *(const bf16x8*)zr;
  const bf16x8 r1 = *(const bf16x8*)(zr + 8);

  const ushort4 qv = *(const ushort4*)&znS[((size_t)b * NN_ + i) * DD + (lane << 2)];
  const float q0 = b2f(qv.x), q1 = b2f(qv.y), q2 = b2f(qv.z), q3 = b2f(qv.w);

  float a4[5], cd[5];
#pragma unroll
  for (int s = 0; s < 5; ++s) {
    const int j = w0 + s;
    float p = 0.f;
    if (j != i) {  // wave-uniform branch
      const ushort* wrp = M2 + mb + (size_t)j * NN_ + (lane << 4);
      const bf16x8 wv0 = *(const bf16x8*)wrp;
      const bf16x8 wv1 = *(const bf16x8*)(wrp + 8);
#pragma unroll
      for (int e = 0; e < 8; ++e)
        p += b2f((ushort)r0[e]) * b2f((ushort)wv0[e]) + b2f((ushort)r1[e]) * b2f((ushort)wv1[e]);
    }
    const ushort4 ov = *(const ushort4*)&znO[((size_t)b * NN_ + j) * DD + (lane << 2)];
    float c = q0 * b2f(ov.x) + q1 * b2f(ov.y) + q2 * b2f(ov.z) + q3 * b2f(ov.w);
#pragma unroll
    for (int o = 32; o; o >>= 1) { p += __shfl_xor(p, o); c += __shfl_xor(c, o); }
    a4[s] = p;
    cd[s] = c;
  }

  const float rsi = rsqrtf(r[(size_t)b * NN_ + i]);
  float num = 0.f;
#pragma unroll
  for (int s = 0; s < 5; ++s) {
    const int j = w0 + s;
    const float g = expf(cd[s] * INV_T);
    if (j == i) {
      num += g;  // strong term
    } else {
      const float d = (float)(j - i);
      const float pw = expf(-d * d * 0.125f);
      const float ratio = sqrtf(r[(size_t)b * NN_ + j]) * rsi;  // sqrt(r_j / r_i)
      const float mband = b2f(M[mb + (size_t)i * NN_ + j]);
      const float m2band = b2f(M2[mb + (size_t)i * NN_ + j]);
      const float sc = 0.5f * pw + ratio * (mband + m2band + a4[s]) * (0.5f / 3.0f);
      num += sc * g;
    }
  }

  if (lane == 0) {
    const float dn = den[(size_t)b * NN_ + i];
    lossRows[(size_t)b * (2 * NN_) + halfOff + i] = -logf(num / (dn + 1e-9f) + 1e-9f);
  }
}

// ---------------- final mean ----------------
__global__ __launch_bounds__(256) void k_final(const float* __restrict__ lossRows, float* __restrict__ out) {
  const int t = threadIdx.x;
  float s = 0.f;
  for (int idx = t; idx < BB * 2 * NN_; idx += 256) s += lossRows[idx];
#pragma unroll
  for (int o = 32; o; o >>= 1) s += __shfl_xor(s, o);
  __shared__ float p[4];
  if ((t & 63) == 0) p[t >> 6] = s;
  __syncthreads();
  if (t == 0) out[0] = (p[0] + p[1] + p[2] + p[3]) / (float)(BB * 2 * NN_);
}

extern "C" void kernel_launch(void* const* d_in, const int* in_sizes, int n_in, void* d_out, int out_size,
                              void* d_ws, size_t ws_size, hipStream_t stream) {
  const float* z1 = (const float*)d_in[0];
  const float* z2 = (const float*)d_in[1];
  float* out = (float*)d_out;

  const size_t nzd = (size_t)BB * NN_ * DD;
  const size_t nnn = (size_t)BB * NN_ * NN_;
  const size_t nv = (size_t)BB * NN_;

  ushort* zn1 = (ushort*)d_ws;
  ushort* zn2 = zn1 + nzd;
  ushort* X = zn2 + nzd;   // E2 -> M(half2)
  ushort* Y = X + nnn;     // E1 -> M(half1)
  ushort* Z = Y + nnn;     // M2^2 then M1^2
  float* den1 = (float*)(Z + nnn);
  float* den2 = den1 + nv;
  float* rsum1 = den2 + nv;
  float* rsum2 = rsum1 + nv;
  float* lossRows = rsum2 + nv;

  const size_t needed = 2 * nzd * 2 + 3 * nnn * 2 + 6 * nv * 4;
  if (ws_size < needed) return;  // fail cleanly instead of faulting

  dim3 blk(256);
  const int gTri = 36 * 2 * 8;   // 576: 36 upper-triangle tiles x 16 batches
  const int gFull = 64 * 2 * 8;  // 1024
  const int gScale = (int)(nnn / 2048);
  const int gLoss = (int)(nv / 4);

  hipMemsetAsync(den1, 0, 4 * nv * 4, stream);  // den1, den2, rsum1, rsum2

  k_norm<<<2 * BB * NN_, blk, 0, stream>>>(z1, z2, zn1);

  // half 2: X = E2 = exp(S22) (sym, dual-store), den2 same-half part, rsum2
  k_gemm_nt<1, DD, 1><<<gTri, blk, 0, stream>>>(zn2, zn2, X, den2, nullptr, rsum2);
  k_scale<<<gScale, blk, 0, stream>>>(X, rsum2);                                        // X = M(h2)
  k_gemm_nt<0, NN_, 1><<<gTri, blk, 0, stream>>>(X, X, Z, nullptr, nullptr, nullptr);   // Z = M2^2

  // cross den contributions (S21 = S12^T) — full grid, no output symmetry
  k_gemm_nt<2, DD, 0><<<gFull, blk, 0, stream>>>(zn1, zn2, nullptr, den1, den2, nullptr);

  // half 1: Y = E1 = exp(S11) (sym, dual-store), den1 same-half part, rsum1
  k_gemm_nt<1, DD, 1><<<gTri, blk, 0, stream>>>(zn1, zn1, Y, den1, nullptr, rsum1);
  k_scale<<<gScale, blk, 0, stream>>>(Y, rsum1);                                        // Y = M(h1)

  // loss rows half 1 (assoc of half 2: X, Z, rsum2; den1)
  k_loss<<<gLoss, blk, 0, stream>>>(X, Z, rsum2, zn1, zn2, den1, lossRows, 0);

  k_gemm_nt<0, NN_, 1><<<gTri, blk, 0, stream>>>(Y, Y, Z, nullptr, nullptr, nullptr);   // Z = M1^2

  // loss rows half 2 (assoc of half 1: Y, Z, rsum1; den2)
  k_loss<<<gLoss, blk, 0, stream>>>(Y, Z, rsum1, zn2, zn1, den2, lossRows, NN_);

  k_final<<<1, blk, 0, stream>>>(lossRows, out);
}

// Round 10
// 296.357 us; speedup vs baseline: 3.0530x; 1.1018x over previous
//
#include <hip/hip_runtime.h>
#include <cmath>
#include <cstdint>

#define BB 16
#define NN_ 1024
#define DD 256

constexpr float INV_T = 1.0f / 0.07f;

typedef __attribute__((ext_vector_type(8))) short bf16x8;
typedef __attribute__((ext_vector_type(4))) float f32x4;

static __device__ __forceinline__ float b2f(ushort u) {
  union { uint i; float f; } c; c.i = ((uint)u) << 16; return c.f;
}
static __device__ __forceinline__ ushort f2b(float f) {
  union { float f; uint i; } c; c.f = f;
  uint r = c.i + 0x7fffu + ((c.i >> 16) & 1u);
  return (ushort)(r >> 16);
}

// async global->LDS, 16B per lane, LDS dest = wave-uniform base + lane*16
static __device__ __forceinline__ void gload16(const void* g, void* l) {
  __builtin_amdgcn_global_load_lds((const __attribute__((address_space(1))) unsigned int*)g,
                                   (__attribute__((address_space(3))) unsigned int*)l, 16, 0, 0);
}

// ---------------- norm (z f32 -> zn bf16) + zero den/rsum vectors ----------------
__global__ __launch_bounds__(256) void k_norm(const float* __restrict__ z1, const float* __restrict__ z2,
                                              ushort* __restrict__ znAll, float* __restrict__ vecs) {
  const int row = blockIdx.x;  // 0 .. 2*BB*NN_-1
  const int t = threadIdx.x;
  if (row < 256) vecs[(row << 8) + t] = 0.f;  // zero den1,den2,rsum1,rsum2 (65536 floats)
  const bool second = row >= BB * NN_;
  const float* z = second ? z2 : z1;
  const size_t inBase = (size_t)(second ? row - BB * NN_ : row) * DD + t;
  float v = z[inBase];
  float ss = v * v;
#pragma unroll
  for (int o = 32; o; o >>= 1) ss += __shfl_xor(ss, o);
  __shared__ float par[4];
  if ((t & 63) == 0) par[t >> 6] = ss;
  __syncthreads();
  float tot = par[0] + par[1] + par[2] + par[3];
  znAll[(size_t)row * DD + t] = f2b(v / (sqrtf(tot) + 1e-12f));
}

// ---------------- mega K=256 GEMM: SIM_SAME(TRI, both halves) + CROSS in one launch ----------------
// blocks [0,1152): SIM tri tiles. m=0: h2 (zn2 -> X, den2/rsum2); m=1: h1 (zn1 -> Y, den1/rsum1).
//   store bf16 exp(acc) + mirror; den += sum exp(acc/T) skip diag (rows + cols); rsum += sum exp(acc).
// blocks [1152,2176): CROSS zn1*zn2^T: den1 += row-sums exp(/T), den2 += col-sums.
__global__ __launch_bounds__(256) void k_mega256(const ushort* __restrict__ znAll, ushort* __restrict__ XY,
                                                 float* __restrict__ den1, float* __restrict__ den2,
                                                 float* __restrict__ rsum1, float* __restrict__ rsum2) {
  __shared__ __align__(16) ushort smem[17408];                 // union {As,Bs | tb}
  ushort (*As)[128][32] = (ushort (*)[128][32])smem;
  ushort (*Bs)[128][32] = (ushort (*)[128][32])(smem + 8192);
  ushort (*tb)[136] = (ushort (*)[136])smem;

  const int t = threadIdx.x;
  const int fid = blockIdx.x;
  const bool isSim = fid < 1152;
  const size_t nzd = (size_t)BB * NN_ * DD;
  int b, row0, col0, m = 0;
  const ushort *baseA, *baseB;
  ushort* C = nullptr;
  float *denR, *denC = nullptr, *rsum = nullptr;
  if (isSim) {
    const int xcd = fid & 7;
    const int j = fid >> 3;            // 0..143
    const int unit = j / 36;
    int rem = j % 36;
    m = unit >> 1;
    b = (xcd << 1) | (unit & 1);
    int r = 0;
#pragma unroll
    for (int q = 0; q < 7; ++q)
      if (rem >= 8 - r) { rem -= 8 - r; ++r; }
    row0 = r << 7;
    col0 = (r + rem) << 7;
    baseA = znAll + (m ? 0 : nzd) + (size_t)b * NN_ * DD;
    baseB = baseA;
    C = XY + (size_t)m * BB * NN_ * NN_ + (size_t)b * NN_ * NN_;
    denR = m ? den1 : den2;
    rsum = m ? rsum1 : rsum2;
  } else {
    const int f2 = fid - 1152;
    const int xcd = f2 & 7;
    const int j = f2 >> 3;             // 0..127
    b = (xcd << 1) | (j >> 6);
    const int jj = j & 63;
    row0 = (jj >> 3) << 7;
    col0 = (jj & 7) << 7;
    baseA = znAll + (size_t)b * NN_ * DD;
    baseB = znAll + nzd + (size_t)b * NN_ * DD;
    denR = den1;
    denC = den2;
  }

  const int lane = t & 63, w = t >> 6;
  const int wr = w >> 1, wc = w & 1;
  const int l15 = lane & 15, slot = lane >> 4;
  const int sRow = lane >> 2;
  const int kg = (lane & 3) ^ ((lane >> 3) & 3);
  const int sCol = kg << 3;
  const ushort* gA0 = baseA + (size_t)(row0 + (w << 5) + sRow) * DD + sCol;
  const ushort* gA1 = gA0 + (size_t)16 * DD;
  const ushort* gB0 = baseB + (size_t)(col0 + (w << 5) + sRow) * DD + sCol;
  const ushort* gB1 = gB0 + (size_t)16 * DD;

  f32x4 acc[4][4];
#pragma unroll
  for (int i = 0; i < 4; ++i)
#pragma unroll
    for (int jx = 0; jx < 4; ++jx)
#pragma unroll
      for (int e = 0; e < 4; ++e) acc[i][jx][e] = 0.f;

  gload16(gA0, &As[0][w << 5][0]);
  gload16(gA1, &As[0][(w << 5) + 16][0]);
  gload16(gB0, &Bs[0][w << 5][0]);
  gload16(gB1, &Bs[0][(w << 5) + 16][0]);
  __syncthreads();

  int cur = 0;
  for (int k0 = 0; k0 < DD; k0 += 32) {
    const int nxt = cur ^ 1;
    if (k0 + 32 < DD) {
      gload16(gA0 + k0 + 32, &As[nxt][w << 5][0]);
      gload16(gA1 + k0 + 32, &As[nxt][(w << 5) + 16][0]);
      gload16(gB0 + k0 + 32, &Bs[nxt][w << 5][0]);
      gload16(gB1 + k0 + 32, &Bs[nxt][(w << 5) + 16][0]);
    }
    bf16x8 af[4], bfv[4];
#pragma unroll
    for (int fr = 0; fr < 4; ++fr) {
      const int r = (wr << 6) + (fr << 4) + l15;
      af[fr] = *(const bf16x8*)&As[cur][r][(slot ^ ((r >> 1) & 3)) << 3];
    }
#pragma unroll
    for (int fc = 0; fc < 4; ++fc) {
      const int r = (wc << 6) + (fc << 4) + l15;
      bfv[fc] = *(const bf16x8*)&Bs[cur][r][(slot ^ ((r >> 1) & 3)) << 3];
    }
#pragma unroll
    for (int fr = 0; fr < 4; ++fr)
#pragma unroll
      for (int fc = 0; fc < 4; ++fc)
        acc[fr][fc] = __builtin_amdgcn_mfma_f32_16x16x32_bf16(af[fr], bfv[fc], acc[fr][fc], 0, 0, 0);
    __syncthreads();
    cur = nxt;
  }

  // Epilogue. C/D layout: col = lane&15, row = (lane>>4)*4 + reg.
  if (isSim) {
    float colp_d[4] = {0.f, 0.f, 0.f, 0.f};
    float colp_e[4] = {0.f, 0.f, 0.f, 0.f};
#pragma unroll
    for (int fr = 0; fr < 4; ++fr) {
#pragma unroll
      for (int jx = 0; jx < 4; ++jx) {
        const int lrow = (wr << 6) + (fr << 4) + (slot << 2) + jx;
        const int grow = row0 + lrow;
        float rs = 0.f, es = 0.f;
#pragma unroll
        for (int fc = 0; fc < 4; ++fc) {
          const int lcol = (wc << 6) + (fc << 4) + l15;
          const int gcol = col0 + lcol;
          const float v = acc[fr][fc][jx];
          const float ev = expf(v);
          const ushort h = f2b(ev);
          C[(size_t)grow * NN_ + gcol] = h;
          tb[lcol][lrow] = h;
          es += ev;
          colp_e[fc] += ev;
          const float dv = expf(v * INV_T);
          if (grow != gcol) { rs += dv; colp_d[fc] += dv; }
        }
#pragma unroll
        for (int o = 1; o < 16; o <<= 1) { rs += __shfl_xor(rs, o); es += __shfl_xor(es, o); }
        if (l15 == 0) {
          atomicAdd(&denR[(size_t)b * NN_ + grow], rs);
          atomicAdd(&rsum[(size_t)b * NN_ + grow], es);
        }
      }
    }
    if (row0 != col0) {  // lower-triangle contributions + mirrored store
#pragma unroll
      for (int fc = 0; fc < 4; ++fc) {
        float cd = colp_d[fc], ce = colp_e[fc];
        cd += __shfl_xor(cd, 16); cd += __shfl_xor(cd, 32);
        ce += __shfl_xor(ce, 16); ce += __shfl_xor(ce, 32);
        if (slot == 0) {
          const int gcol = col0 + (wc << 6) + (fc << 4) + l15;
          atomicAdd(&denR[(size_t)b * NN_ + gcol], cd);
          atomicAdd(&rsum[(size_t)b * NN_ + gcol], ce);
        }
      }
      __syncthreads();
#pragma unroll
      for (int rep = 0; rep < 8; ++rep) {
        const int cid = rep * 256 + t;
        const int rr = cid >> 4;
        const int c8 = (cid & 15) << 3;
        *(uint4*)&C[(size_t)(col0 + rr) * NN_ + row0 + c8] = *(const uint4*)&tb[rr][c8];
      }
    }
  } else {  // CROSS
    float colp[4] = {0.f, 0.f, 0.f, 0.f};
#pragma unroll
    for (int fr = 0; fr < 4; ++fr) {
#pragma unroll
      for (int jx = 0; jx < 4; ++jx) {
        const int grow = row0 + (wr << 6) + (fr << 4) + (slot << 2) + jx;
        float rs = 0.f;
#pragma unroll
        for (int fc = 0; fc < 4; ++fc) {
          const float e = expf(acc[fr][fc][jx] * INV_T);
          rs += e;
          colp[fc] += e;
        }
#pragma unroll
        for (int o = 1; o < 16; o <<= 1) rs += __shfl_xor(rs, o);
        if (l15 == 0) atomicAdd(&denR[(size_t)b * NN_ + grow], rs);
      }
    }
#pragma unroll
    for (int fc = 0; fc < 4; ++fc) {
      float cs = colp[fc];
      cs += __shfl_xor(cs, 16);
      cs += __shfl_xor(cs, 32);
      if (slot == 0) atomicAdd(&denC[(size_t)b * NN_ + col0 + (wc << 6) + (fc << 4) + l15], cs);
    }
  }
}

// ---------------- scale both halves: M = E * rsqrt(r_i) * rsqrt(r_j), in place ----------------
__global__ __launch_bounds__(256) void k_scale(ushort* __restrict__ XY, const float* __restrict__ rsum1,
                                               const float* __restrict__ rsum2) {
  const size_t idx8 = ((size_t)blockIdx.x * 256 + threadIdx.x) << 3;  // 8 elems/thread over [0, 2*nnn)
  const size_t nnn = (size_t)BB * NN_ * NN_;
  const int m = idx8 >= nnn;                 // 0: X(h2)<->rsum2, 1: Y(h1)<->rsum1
  const float* r = m ? rsum1 : rsum2;
  const size_t loc = idx8 - (size_t)m * nnn;
  const int grow = (int)(loc >> 10);         // b*NN_ + i
  const int bcol = (int)(loc & 1023);
  const int batch = grow >> 10;
  const float rsi = rsqrtf(r[grow]);
  bf16x8 v = *(const bf16x8*)&XY[idx8];
  const float* rb = r + (batch << 10) + bcol;
  const float4 rc0 = *(const float4*)rb;
  const float4 rc1 = *(const float4*)(rb + 4);
  float rj[8] = {rc0.x, rc0.y, rc0.z, rc0.w, rc1.x, rc1.y, rc1.z, rc1.w};
  bf16x8 o;
#pragma unroll
  for (int e = 0; e < 8; ++e) {
    const float wgt = rsi * rsqrtf(rj[e]);   // commutative product -> M bit-symmetric
    o[e] = (short)f2b(b2f((ushort)v[e]) * wgt);
  }
  *(bf16x8*)&XY[idx8] = o;
}

// ---------------- mega SQ: Z = X*X^T and W = Y*Y^T (TRI, mirror store), one launch ----------------
__global__ __launch_bounds__(256) void k_megasq(const ushort* __restrict__ XY, ushort* __restrict__ ZW) {
  __shared__ __align__(16) ushort smem[17408];
  ushort (*As)[128][32] = (ushort (*)[128][32])smem;
  ushort (*Bs)[128][32] = (ushort (*)[128][32])(smem + 8192);
  ushort (*tb)[136] = (ushort (*)[136])smem;

  const int t = threadIdx.x;
  const int fid = blockIdx.x;
  const int xcd = fid & 7;
  const int j = fid >> 3;        // 0..143
  const int unit = j / 36;
  int rem = j % 36;
  const int m = unit >> 1;
  const int b = (xcd << 1) | (unit & 1);
  int r = 0;
#pragma unroll
  for (int q = 0; q < 7; ++q)
    if (rem >= 8 - r) { rem -= 8 - r; ++r; }
  const int row0 = r << 7;
  const int col0 = (r + rem) << 7;

  const size_t nnn = (size_t)BB * NN_ * NN_;
  const ushort* baseA = XY + (size_t)m * nnn + (size_t)b * NN_ * NN_;
  ushort* C = ZW + (size_t)m * nnn + (size_t)b * NN_ * NN_;

  const int lane = t & 63, w = t >> 6;
  const int wr = w >> 1, wc = w & 1;
  const int l15 = lane & 15, slot = lane >> 4;
  const int sRow = lane >> 2;
  const int kg = (lane & 3) ^ ((lane >> 3) & 3);
  const int sCol = kg << 3;
  const ushort* gA0 = baseA + (size_t)(row0 + (w << 5) + sRow) * NN_ + sCol;
  const ushort* gA1 = gA0 + (size_t)16 * NN_;
  const ushort* gB0 = baseA + (size_t)(col0 + (w << 5) + sRow) * NN_ + sCol;
  const ushort* gB1 = gB0 + (size_t)16 * NN_;

  f32x4 acc[4][4];
#pragma unroll
  for (int i = 0; i < 4; ++i)
#pragma unroll
    for (int jx = 0; jx < 4; ++jx)
#pragma unroll
      for (int e = 0; e < 4; ++e) acc[i][jx][e] = 0.f;

  gload16(gA0, &As[0][w << 5][0]);
  gload16(gA1, &As[0][(w << 5) + 16][0]);
  gload16(gB0, &Bs[0][w << 5][0]);
  gload16(gB1, &Bs[0][(w << 5) + 16][0]);
  __syncthreads();

  int cur = 0;
  for (int k0 = 0; k0 < NN_; k0 += 32) {
    const int nxt = cur ^ 1;
    if (k0 + 32 < NN_) {
      gload16(gA0 + k0 + 32, &As[nxt][w << 5][0]);
      gload16(gA1 + k0 + 32, &As[nxt][(w << 5) + 16][0]);
      gload16(gB0 + k0 + 32, &Bs[nxt][w << 5][0]);
      gload16(gB1 + k0 + 32, &Bs[nxt][(w << 5) + 16][0]);
    }
    bf16x8 af[4], bfv[4];
#pragma unroll
    for (int fr = 0; fr < 4; ++fr) {
      const int rr = (wr << 6) + (fr << 4) + l15;
      af[fr] = *(const bf16x8*)&As[cur][rr][(slot ^ ((rr >> 1) & 3)) << 3];
    }
#pragma unroll
    for (int fc = 0; fc < 4; ++fc) {
      const int rr = (wc << 6) + (fc << 4) + l15;
      bfv[fc] = *(const bf16x8*)&Bs[cur][rr][(slot ^ ((rr >> 1) & 3)) << 3];
    }
#pragma unroll
    for (int fr = 0; fr < 4; ++fr)
#pragma unroll
      for (int fc = 0; fc < 4; ++fc)
        acc[fr][fc] = __builtin_amdgcn_mfma_f32_16x16x32_bf16(af[fr], bfv[fc], acc[fr][fc], 0, 0, 0);
    __syncthreads();
    cur = nxt;
  }

#pragma unroll
  for (int fr = 0; fr < 4; ++fr) {
#pragma unroll
    for (int jx = 0; jx < 4; ++jx) {
      const int lrow = (wr << 6) + (fr << 4) + (slot << 2) + jx;
      const int grow = row0 + lrow;
#pragma unroll
      for (int fc = 0; fc < 4; ++fc) {
        const int lcol = (wc << 6) + (fc << 4) + l15;
        const ushort h = f2b(acc[fr][fc][jx]);
        C[(size_t)grow * NN_ + col0 + lcol] = h;
        tb[lcol][lrow] = h;
      }
    }
  }
  if (row0 != col0) {
    __syncthreads();
#pragma unroll
    for (int rep = 0; rep < 8; ++rep) {
      const int cid = rep * 256 + t;
      const int rr = cid >> 4;
      const int c8 = (cid & 15) << 3;
      *(uint4*)&C[(size_t)(col0 + rr) * NN_ + row0 + c8] = *(const uint4*)&tb[rr][c8];
    }
  }
}

// ---------------- mega loss: both halves; writes loss into the row's own den slot ----------------
__global__ __launch_bounds__(256) void k_megaloss(const ushort* __restrict__ XY, const ushort* __restrict__ ZW,
                                                  const ushort* __restrict__ znAll,
                                                  const float* __restrict__ rsum1, const float* __restrict__ rsum2,
                                                  float* __restrict__ den1, float* __restrict__ den2) {
  const int gid = (blockIdx.x << 2) + (threadIdx.x >> 6);  // 0..32767, one wave per row
  const int lane = threadIdx.x & 63;
  const int h = gid >> 14;                                 // 0: z1 rows (assoc h2), 1: z2 rows
  const int lr = gid & 16383;
  const int b = lr >> 10, i = lr & 1023;
  const size_t nnn = (size_t)BB * NN_ * NN_;
  const size_t nzd = (size_t)BB * NN_ * DD;
  const ushort* M = XY + (size_t)h * nnn + (size_t)b * NN_ * NN_;
  const ushort* M2 = ZW + (size_t)h * nnn + (size_t)b * NN_ * NN_;
  const float* r = h ? rsum1 : rsum2;
  float* den = h ? den2 : den1;
  const ushort* znS = znAll + (size_t)h * nzd;
  const ushort* znO = znAll + (size_t)(1 - h) * nzd;
  const int w0 = min(max(i - 2, 0), NN_ - 5);

  const ushort* zr = M2 + (size_t)i * NN_ + (lane << 4);
  const bf16x8 r0 = *(const bf16x8*)zr;
  const bf16x8 r1 = *(const bf16x8*)(zr + 8);

  const ushort4 qv = *(const ushort4*)&znS[((size_t)b * NN_ + i) * DD + (lane << 2)];
  const float q0 = b2f(qv.x), q1 = b2f(qv.y), q2 = b2f(qv.z), q3 = b2f(qv.w);

  float a4[5], cd[5];
#pragma unroll
  for (int s = 0; s < 5; ++s) {
    const int jx = w0 + s;
    float p = 0.f;
    if (jx != i) {  // wave-uniform branch
      const ushort* wrp = M2 + (size_t)jx * NN_ + (lane << 4);
      const bf16x8 wv0 = *(const bf16x8*)wrp;
      const bf16x8 wv1 = *(const bf16x8*)(wrp + 8);
#pragma unroll
      for (int e = 0; e < 8; ++e)
        p += b2f((ushort)r0[e]) * b2f((ushort)wv0[e]) + b2f((ushort)r1[e]) * b2f((ushort)wv1[e]);
    }
    const ushort4 ov = *(const ushort4*)&znO[((size_t)b * NN_ + jx) * DD + (lane << 2)];
    float c = q0 * b2f(ov.x) + q1 * b2f(ov.y) + q2 * b2f(ov.z) + q3 * b2f(ov.w);
#pragma unroll
    for (int o = 32; o; o >>= 1) { p += __shfl_xor(p, o); c += __shfl_xor(c, o); }
    a4[s] = p;
    cd[s] = c;
  }

  const float rsi = rsqrtf(r[(size_t)b * NN_ + i]);
  float num = 0.f;
#pragma unroll
  for (int s = 0; s < 5; ++s) {
    const int jx = w0 + s;
    const float g = expf(cd[s] * INV_T);
    if (jx == i) {
      num += g;  // strong term
    } else {
      const float d = (float)(jx - i);
      const float pw = expf(-d * d * 0.125f);
      const float ratio = sqrtf(r[(size_t)b * NN_ + jx]) * rsi;  // sqrt(r_j / r_i)
      const float mband = b2f(M[(size_t)i * NN_ + jx]);
      const float m2band = b2f(M2[(size_t)i * NN_ + jx]);
      const float sc = 0.5f * pw + ratio * (mband + m2band + a4[s]) * (0.5f / 3.0f);
      num += sc * g;
    }
  }

  if (lane == 0) {
    const float dn = den[(size_t)b * NN_ + i];                 // read own slot...
    den[(size_t)b * NN_ + i] = -logf(num / (dn + 1e-9f) + 1e-9f);  // ...then overwrite with loss
  }
}

// ---------------- final mean over den1||den2 (2*BB*NN_ floats, contiguous) ----------------
__global__ __launch_bounds__(256) void k_final(const float* __restrict__ lossRows, float* __restrict__ out) {
  const int t = threadIdx.x;
  float s = 0.f;
  for (int idx = t; idx < BB * 2 * NN_; idx += 256) s += lossRows[idx];
#pragma unroll
  for (int o = 32; o; o >>= 1) s += __shfl_xor(s, o);
  __shared__ float p[4];
  if ((t & 63) == 0) p[t >> 6] = s;
  __syncthreads();
  if (t == 0) out[0] = (p[0] + p[1] + p[2] + p[3]) / (float)(BB * 2 * NN_);
}

extern "C" void kernel_launch(void* const* d_in, const int* in_sizes, int n_in, void* d_out, int out_size,
                              void* d_ws, size_t ws_size, hipStream_t stream) {
  const float* z1 = (const float*)d_in[0];
  const float* z2 = (const float*)d_in[1];
  float* out = (float*)d_out;

  const size_t nzd = (size_t)BB * NN_ * DD;
  const size_t nnn = (size_t)BB * NN_ * NN_;
  const size_t nv = (size_t)BB * NN_;

  ushort* znAll = (ushort*)d_ws;                // 2*nzd
  ushort* XY = znAll + 2 * nzd;                 // X (h2 M) then Y (h1 M): 2*nnn
  ushort* ZW = XY + 2 * nnn;                    // Z (h2 M^2) then W (h1 M^2): 2*nnn
  float* den1 = (float*)(ZW + 2 * nnn);         // den1, den2, rsum1, rsum2: 4*nv
  float* den2 = den1 + nv;
  float* rsum1 = den2 + nv;
  float* rsum2 = rsum1 + nv;

  const size_t needed = 2 * nzd * 2 + 4 * nnn * 2 + 4 * nv * 4;  // 151,257,088 B (round-6 proven)
  if (ws_size < needed) return;  // fail cleanly instead of faulting

  dim3 blk(256);

  // 1) norm + zero vectors
  k_norm<<<2 * BB * NN_, blk, 0, stream>>>(z1, z2, znAll, den1);

  // 2) SIM_SAME(h2 -> X) + SIM_SAME(h1 -> Y) + CROSS, one launch
  k_mega256<<<1152 + 1024, blk, 0, stream>>>(znAll, XY, den1, den2, rsum1, rsum2);

  // 3) scale both halves in place: X,Y -> M(h2), M(h1)
  k_scale<<<(int)(2 * nnn / 2048), blk, 0, stream>>>(XY, rsum1, rsum2);

  // 4) Z = M(h2)^2, W = M(h1)^2, one launch (TRI + mirror)
  k_megasq<<<1152, blk, 0, stream>>>(XY, ZW);

  // 5) both loss halves; loss written into den slots
  k_megaloss<<<(int)(2 * nv / 4), blk, 0, stream>>>(XY, ZW, znAll, rsum1, rsum2, den1, den2);

  // 6) mean over den1||den2
  k_final<<<1, blk, 0, stream>>>(den1, out);
}

// Round 11
// 269.117 us; speedup vs baseline: 3.3621x; 1.1012x over previous
//
#include <hip/hip_runtime.h>
#include <cmath>
#include <cstdint>

#define BB 16
#define NN_ 1024
#define DD 256

constexpr float INV_T = 1.0f / 0.07f;

typedef __attribute__((ext_vector_type(8))) short bf16x8;
typedef __attribute__((ext_vector_type(4))) float f32x4;

static __device__ __forceinline__ float b2f(ushort u) {
  union { uint i; float f; } c; c.i = ((uint)u) << 16; return c.f;
}
static __device__ __forceinline__ ushort f2b(float f) {
  union { float f; uint i; } c; c.f = f;
  uint r = c.i + 0x7fffu + ((c.i >> 16) & 1u);
  return (ushort)(r >> 16);
}

// async global->LDS, 16B per lane, LDS dest = wave-uniform base + lane*16
static __device__ __forceinline__ void gload16(const void* g, void* l) {
  __builtin_amdgcn_global_load_lds((const __attribute__((address_space(1))) unsigned int*)g,
                                   (__attribute__((address_space(3))) unsigned int*)l, 16, 0, 0);
}

// ---------------- norm: wave-per-row (4 rows/block), f32->bf16; + zero den/rsum vectors ----------------
__global__ __launch_bounds__(256) void k_norm(const float* __restrict__ z1, const float* __restrict__ z2,
                                              ushort* __restrict__ znAll, float* __restrict__ vecs) {
  if (blockIdx.x < 256) vecs[(blockIdx.x << 8) + threadIdx.x] = 0.f;  // 65536 floats: den1,den2,rsum1,rsum2
  const int row = (blockIdx.x << 2) + (threadIdx.x >> 6);  // 0 .. 2*BB*NN_-1
  const int lane = threadIdx.x & 63;
  const bool second = row >= BB * NN_;
  const float* z = second ? z2 : z1;
  const size_t rbase = (size_t)(second ? row - BB * NN_ : row) * DD;
  const float4 v = ((const float4*)(z + rbase))[lane];
  float ss = v.x * v.x + v.y * v.y + v.z * v.z + v.w * v.w;
#pragma unroll
  for (int o = 32; o; o >>= 1) ss += __shfl_xor(ss, o);
  const float inv = 1.0f / (sqrtf(ss) + 1e-12f);
  ushort4 o4;
  o4.x = f2b(v.x * inv); o4.y = f2b(v.y * inv); o4.z = f2b(v.z * inv); o4.w = f2b(v.w * inv);
  ((ushort4*)(znAll + (size_t)row * DD))[lane] = o4;
}

// ---------------- mega K=256 GEMM: SIM_SAME(TRI, both halves) + CROSS in one launch ----------------
// blocks [0,1152): SIM tri tiles. m=0: h2 (zn2 -> X, den2/rsum2); m=1: h1 (zn1 -> Y, den1/rsum1).
//   store bf16 exp(acc) + mirror; den += sum exp(acc/T) skip diag (rows + cols); rsum += sum exp(acc).
// blocks [1152,2176): CROSS zn1*zn2^T: den1 += row-sums exp(/T), den2 += col-sums.
__global__ __launch_bounds__(256) void k_mega256(const ushort* __restrict__ znAll, ushort* __restrict__ XY,
                                                 float* __restrict__ den1, float* __restrict__ den2,
                                                 float* __restrict__ rsum1, float* __restrict__ rsum2) {
  __shared__ __align__(16) ushort smem[17408];                 // union {As,Bs | tb}
  ushort (*As)[128][32] = (ushort (*)[128][32])smem;
  ushort (*Bs)[128][32] = (ushort (*)[128][32])(smem + 8192);
  ushort (*tb)[136] = (ushort (*)[136])smem;

  const int t = threadIdx.x;
  const int fid = blockIdx.x;
  const bool isSim = fid < 1152;
  const size_t nzd = (size_t)BB * NN_ * DD;
  int b, row0, col0, m = 0;
  const ushort *baseA, *baseB;
  ushort* C = nullptr;
  float *denR, *denC = nullptr, *rsum = nullptr;
  if (isSim) {
    const int xcd = fid & 7;
    const int j = fid >> 3;            // 0..143
    const int unit = j / 36;
    int rem = j % 36;
    m = unit >> 1;
    b = (xcd << 1) | (unit & 1);
    int r = 0;
#pragma unroll
    for (int q = 0; q < 7; ++q)
      if (rem >= 8 - r) { rem -= 8 - r; ++r; }
    row0 = r << 7;
    col0 = (r + rem) << 7;
    baseA = znAll + (m ? 0 : nzd) + (size_t)b * NN_ * DD;
    baseB = baseA;
    C = XY + (size_t)m * BB * NN_ * NN_ + (size_t)b * NN_ * NN_;
    denR = m ? den1 : den2;
    rsum = m ? rsum1 : rsum2;
  } else {
    const int f2 = fid - 1152;
    const int xcd = f2 & 7;
    const int j = f2 >> 3;             // 0..127
    b = (xcd << 1) | (j >> 6);
    const int jj = j & 63;
    row0 = (jj >> 3) << 7;
    col0 = (jj & 7) << 7;
    baseA = znAll + (size_t)b * NN_ * DD;
    baseB = znAll + nzd + (size_t)b * NN_ * DD;
    denR = den1;
    denC = den2;
  }

  const int lane = t & 63, w = t >> 6;
  const int wr = w >> 1, wc = w & 1;
  const int l15 = lane & 15, slot = lane >> 4;
  const int sRow = lane >> 2;
  const int kg = (lane & 3) ^ ((lane >> 3) & 3);
  const int sCol = kg << 3;
  const ushort* gA0 = baseA + (size_t)(row0 + (w << 5) + sRow) * DD + sCol;
  const ushort* gA1 = gA0 + (size_t)16 * DD;
  const ushort* gB0 = baseB + (size_t)(col0 + (w << 5) + sRow) * DD + sCol;
  const ushort* gB1 = gB0 + (size_t)16 * DD;

  f32x4 acc[4][4];
#pragma unroll
  for (int i = 0; i < 4; ++i)
#pragma unroll
    for (int jx = 0; jx < 4; ++jx)
#pragma unroll
      for (int e = 0; e < 4; ++e) acc[i][jx][e] = 0.f;

  gload16(gA0, &As[0][w << 5][0]);
  gload16(gA1, &As[0][(w << 5) + 16][0]);
  gload16(gB0, &Bs[0][w << 5][0]);
  gload16(gB1, &Bs[0][(w << 5) + 16][0]);
  __syncthreads();

  int cur = 0;
  for (int k0 = 0; k0 < DD; k0 += 32) {
    const int nxt = cur ^ 1;
    if (k0 + 32 < DD) {
      gload16(gA0 + k0 + 32, &As[nxt][w << 5][0]);
      gload16(gA1 + k0 + 32, &As[nxt][(w << 5) + 16][0]);
      gload16(gB0 + k0 + 32, &Bs[nxt][w << 5][0]);
      gload16(gB1 + k0 + 32, &Bs[nxt][(w << 5) + 16][0]);
    }
    bf16x8 af[4], bfv[4];
#pragma unroll
    for (int fr = 0; fr < 4; ++fr) {
      const int r = (wr << 6) + (fr << 4) + l15;
      af[fr] = *(const bf16x8*)&As[cur][r][(slot ^ ((r >> 1) & 3)) << 3];
    }
#pragma unroll
    for (int fc = 0; fc < 4; ++fc) {
      const int r = (wc << 6) + (fc << 4) + l15;
      bfv[fc] = *(const bf16x8*)&Bs[cur][r][(slot ^ ((r >> 1) & 3)) << 3];
    }
#pragma unroll
    for (int fr = 0; fr < 4; ++fr)
#pragma unroll
      for (int fc = 0; fc < 4; ++fc)
        acc[fr][fc] = __builtin_amdgcn_mfma_f32_16x16x32_bf16(af[fr], bfv[fc], acc[fr][fc], 0, 0, 0);
    __syncthreads();
    cur = nxt;
  }

  // Epilogue. C/D layout: col = lane&15, row = (lane>>4)*4 + reg.
  if (isSim) {
    float colp_d[4] = {0.f, 0.f, 0.f, 0.f};
    float colp_e[4] = {0.f, 0.f, 0.f, 0.f};
#pragma unroll
    for (int fr = 0; fr < 4; ++fr) {
#pragma unroll
      for (int jx = 0; jx < 4; ++jx) {
        const int lrow = (wr << 6) + (fr << 4) + (slot << 2) + jx;
        const int grow = row0 + lrow;
        float rs = 0.f, es = 0.f;
#pragma unroll
        for (int fc = 0; fc < 4; ++fc) {
          const int lcol = (wc << 6) + (fc << 4) + l15;
          const int gcol = col0 + lcol;
          const float v = acc[fr][fc][jx];
          const float ev = __expf(v);
          const ushort h = f2b(ev);
          C[(size_t)grow * NN_ + gcol] = h;
          tb[lcol][lrow] = h;
          es += ev;
          colp_e[fc] += ev;
          const float dv = __expf(v * INV_T);
          if (grow != gcol) { rs += dv; colp_d[fc] += dv; }
        }
#pragma unroll
        for (int o = 1; o < 16; o <<= 1) { rs += __shfl_xor(rs, o); es += __shfl_xor(es, o); }
        if (l15 == 0) {
          atomicAdd(&denR[(size_t)b * NN_ + grow], rs);
          atomicAdd(&rsum[(size_t)b * NN_ + grow], es);
        }
      }
    }
    if (row0 != col0) {  // lower-triangle contributions + mirrored store
#pragma unroll
      for (int fc = 0; fc < 4; ++fc) {
        float cd = colp_d[fc], ce = colp_e[fc];
        cd += __shfl_xor(cd, 16); cd += __shfl_xor(cd, 32);
        ce += __shfl_xor(ce, 16); ce += __shfl_xor(ce, 32);
        if (slot == 0) {
          const int gcol = col0 + (wc << 6) + (fc << 4) + l15;
          atomicAdd(&denR[(size_t)b * NN_ + gcol], cd);
          atomicAdd(&rsum[(size_t)b * NN_ + gcol], ce);
        }
      }
      __syncthreads();
#pragma unroll
      for (int rep = 0; rep < 8; ++rep) {
        const int cid = rep * 256 + t;
        const int rr = cid >> 4;
        const int c8 = (cid & 15) << 3;
        *(uint4*)&C[(size_t)(col0 + rr) * NN_ + row0 + c8] = *(const uint4*)&tb[rr][c8];
      }
    }
  } else {  // CROSS
    float colp[4] = {0.f, 0.f, 0.f, 0.f};
#pragma unroll
    for (int fr = 0; fr < 4; ++fr) {
#pragma unroll
      for (int jx = 0; jx < 4; ++jx) {
        const int grow = row0 + (wr << 6) + (fr << 4) + (slot << 2) + jx;
        float rs = 0.f;
#pragma unroll
        for (int fc = 0; fc < 4; ++fc) {
          const float e = __expf(acc[fr][fc][jx] * INV_T);
          rs += e;
          colp[fc] += e;
        }
#pragma unroll
        for (int o = 1; o < 16; o <<= 1) rs += __shfl_xor(rs, o);
        if (l15 == 0) atomicAdd(&denR[(size_t)b * NN_ + grow], rs);
      }
    }
#pragma unroll
    for (int fc = 0; fc < 4; ++fc) {
      float cs = colp[fc];
      cs += __shfl_xor(cs, 16);
      cs += __shfl_xor(cs, 32);
      if (slot == 0) atomicAdd(&denC[(size_t)b * NN_ + col0 + (wc << 6) + (fc << 4) + l15], cs);
    }
  }
}

// ---------------- scale both halves: M = E * rsqrt(r_i) * rsqrt(r_j), in place ----------------
__global__ __launch_bounds__(256) void k_scale(ushort* __restrict__ XY, const float* __restrict__ rsum1,
                                               const float* __restrict__ rsum2) {
  const size_t idx8 = ((size_t)blockIdx.x * 256 + threadIdx.x) << 3;  // 8 elems/thread over [0, 2*nnn)
  const size_t nnn = (size_t)BB * NN_ * NN_;
  const int m = idx8 >= nnn;                 // 0: X(h2)<->rsum2, 1: Y(h1)<->rsum1
  const float* r = m ? rsum1 : rsum2;
  const size_t loc = idx8 - (size_t)m * nnn;
  const int grow = (int)(loc >> 10);         // b*NN_ + i
  const int bcol = (int)(loc & 1023);
  const int batch = grow >> 10;
  const float rsi = rsqrtf(r[grow]);
  bf16x8 v = *(const bf16x8*)&XY[idx8];
  const float* rb = r + (batch << 10) + bcol;
  const float4 rc0 = *(const float4*)rb;
  const float4 rc1 = *(const float4*)(rb + 4);
  float rj[8] = {rc0.x, rc0.y, rc0.z, rc0.w, rc1.x, rc1.y, rc1.z, rc1.w};
  bf16x8 o;
#pragma unroll
  for (int e = 0; e < 8; ++e) {
    const float wgt = rsi * rsqrtf(rj[e]);   // commutative product -> M bit-symmetric
    o[e] = (short)f2b(b2f((ushort)v[e]) * wgt);
  }
  *(bf16x8*)&XY[idx8] = o;
}

// ---------------- mega SQ: Z = X*X^T and W = Y*Y^T (TRI, mirror store), one launch ----------------
__global__ __launch_bounds__(256) void k_megasq(const ushort* __restrict__ XY, ushort* __restrict__ ZW) {
  __shared__ __align__(16) ushort smem[17408];
  ushort (*As)[128][32] = (ushort (*)[128][32])smem;
  ushort (*Bs)[128][32] = (ushort (*)[128][32])(smem + 8192);
  ushort (*tb)[136] = (ushort (*)[136])smem;

  const int t = threadIdx.x;
  const int fid = blockIdx.x;
  const int xcd = fid & 7;
  const int j = fid >> 3;        // 0..143
  const int unit = j / 36;
  int rem = j % 36;
  const int m = unit >> 1;
  const int b = (xcd << 1) | (unit & 1);
  int r = 0;
#pragma unroll
  for (int q = 0; q < 7; ++q)
    if (rem >= 8 - r) { rem -= 8 - r; ++r; }
  const int row0 = r << 7;
  const int col0 = (r + rem) << 7;

  const size_t nnn = (size_t)BB * NN_ * NN_;
  const ushort* baseA = XY + (size_t)m * nnn + (size_t)b * NN_ * NN_;
  ushort* C = ZW + (size_t)m * nnn + (size_t)b * NN_ * NN_;

  const int lane = t & 63, w = t >> 6;
  const int wr = w >> 1, wc = w & 1;
  const int l15 = lane & 15, slot = lane >> 4;
  const int sRow = lane >> 2;
  const int kg = (lane & 3) ^ ((lane >> 3) & 3);
  const int sCol = kg << 3;
  const ushort* gA0 = baseA + (size_t)(row0 + (w << 5) + sRow) * NN_ + sCol;
  const ushort* gA1 = gA0 + (size_t)16 * NN_;
  const ushort* gB0 = baseA + (size_t)(col0 + (w << 5) + sRow) * NN_ + sCol;
  const ushort* gB1 = gB0 + (size_t)16 * NN_;

  f32x4 acc[4][4];
#pragma unroll
  for (int i = 0; i < 4; ++i)
#pragma unroll
    for (int jx = 0; jx < 4; ++jx)
#pragma unroll
      for (int e = 0; e < 4; ++e) acc[i][jx][e] = 0.f;

  gload16(gA0, &As[0][w << 5][0]);
  gload16(gA1, &As[0][(w << 5) + 16][0]);
  gload16(gB0, &Bs[0][w << 5][0]);
  gload16(gB1, &Bs[0][(w << 5) + 16][0]);
  __syncthreads();

  int cur = 0;
  for (int k0 = 0; k0 < NN_; k0 += 32) {
    const int nxt = cur ^ 1;
    if (k0 + 32 < NN_) {
      gload16(gA0 + k0 + 32, &As[nxt][w << 5][0]);
      gload16(gA1 + k0 + 32, &As[nxt][(w << 5) + 16][0]);
      gload16(gB0 + k0 + 32, &Bs[nxt][w << 5][0]);
      gload16(gB1 + k0 + 32, &Bs[nxt][(w << 5) + 16][0]);
    }
    bf16x8 af[4], bfv[4];
#pragma unroll
    for (int fr = 0; fr < 4; ++fr) {
      const int rr = (wr << 6) + (fr << 4) + l15;
      af[fr] = *(const bf16x8*)&As[cur][rr][(slot ^ ((rr >> 1) & 3)) << 3];
    }
#pragma unroll
    for (int fc = 0; fc < 4; ++fc) {
      const int rr = (wc << 6) + (fc << 4) + l15;
      bfv[fc] = *(const bf16x8*)&Bs[cur][rr][(slot ^ ((rr >> 1) & 3)) << 3];
    }
#pragma unroll
    for (int fr = 0; fr < 4; ++fr)
#pragma unroll
      for (int fc = 0; fc < 4; ++fc)
        acc[fr][fc] = __builtin_amdgcn_mfma_f32_16x16x32_bf16(af[fr], bfv[fc], acc[fr][fc], 0, 0, 0);
    __syncthreads();
    cur = nxt;
  }

#pragma unroll
  for (int fr = 0; fr < 4; ++fr) {
#pragma unroll
    for (int jx = 0; jx < 4; ++jx) {
      const int lrow = (wr << 6) + (fr << 4) + (slot << 2) + jx;
      const int grow = row0 + lrow;
#pragma unroll
      for (int fc = 0; fc < 4; ++fc) {
        const int lcol = (wc << 6) + (fc << 4) + l15;
        const ushort h = f2b(acc[fr][fc][jx]);
        C[(size_t)grow * NN_ + col0 + lcol] = h;
        tb[lcol][lrow] = h;
      }
    }
  }
  if (row0 != col0) {
    __syncthreads();
#pragma unroll
    for (int rep = 0; rep < 8; ++rep) {
      const int cid = rep * 256 + t;
      const int rr = cid >> 4;
      const int c8 = (cid & 15) << 3;
      *(uint4*)&C[(size_t)(col0 + rr) * NN_ + row0 + c8] = *(const uint4*)&tb[rr][c8];
    }
  }
}

// ---------------- mega loss: both halves; XCD-affinity block swizzle for M2-row L2 reuse ----------------
__global__ __launch_bounds__(256) void k_megaloss(const ushort* __restrict__ XY, const ushort* __restrict__ ZW,
                                                  const ushort* __restrict__ znAll,
                                                  const float* __restrict__ rsum1, const float* __restrict__ rsum2,
                                                  float* __restrict__ den1, float* __restrict__ den2) {
  // swizzle: XCD x owns 1024 consecutive blocks = 4096 consecutive rows (its M2 slice stays in its L2)
  const int fid = blockIdx.x;               // 0..8191
  const int blk = ((fid & 7) << 10) | (fid >> 3);
  const int gid = (blk << 2) + (threadIdx.x >> 6);  // 0..32767, one wave per row
  const int lane = threadIdx.x & 63;
  const int h = gid >> 14;                  // 0: z1 rows (assoc h2), 1: z2 rows
  const int lr = gid & 16383;
  const int b = lr >> 10, i = lr & 1023;
  const size_t nnn = (size_t)BB * NN_ * NN_;
  const size_t nzd = (size_t)BB * NN_ * DD;
  const ushort* M = XY + (size_t)h * nnn + (size_t)b * NN_ * NN_;
  const ushort* M2 = ZW + (size_t)h * nnn + (size_t)b * NN_ * NN_;
  const float* r = h ? rsum1 : rsum2;
  float* den = h ? den2 : den1;
  const ushort* znS = znAll + (size_t)h * nzd;
  const ushort* znO = znAll + (size_t)(1 - h) * nzd;
  const int w0 = min(max(i - 2, 0), NN_ - 5);

  const ushort* zr = M2 + (size_t)i * NN_ + (lane << 4);
  const bf16x8 r0 = *(const bf16x8*)zr;
  const bf16x8 r1 = *(const bf16x8*)(zr + 8);

  const ushort4 qv = *(const ushort4*)&znS[((size_t)b * NN_ + i) * DD + (lane << 2)];
  const float q0 = b2f(qv.x), q1 = b2f(qv.y), q2 = b2f(qv.z), q3 = b2f(qv.w);

  float a4[5], cd[5];
#pragma unroll
  for (int s = 0; s < 5; ++s) {
    const int jx = w0 + s;
    float p = 0.f;
    if (jx != i) {  // wave-uniform branch
      const ushort* wrp = M2 + (size_t)jx * NN_ + (lane << 4);
      const bf16x8 wv0 = *(const bf16x8*)wrp;
      const bf16x8 wv1 = *(const bf16x8*)(wrp + 8);
#pragma unroll
      for (int e = 0; e < 8; ++e)
        p += b2f((ushort)r0[e]) * b2f((ushort)wv0[e]) + b2f((ushort)r1[e]) * b2f((ushort)wv1[e]);
    }
    const ushort4 ov = *(const ushort4*)&znO[((size_t)b * NN_ + jx) * DD + (lane << 2)];
    float c = q0 * b2f(ov.x) + q1 * b2f(ov.y) + q2 * b2f(ov.z) + q3 * b2f(ov.w);
#pragma unroll
    for (int o = 32; o; o >>= 1) { p += __shfl_xor(p, o); c += __shfl_xor(c, o); }
    a4[s] = p;
    cd[s] = c;
  }

  const float rsi = rsqrtf(r[(size_t)b * NN_ + i]);
  float num = 0.f;
#pragma unroll
  for (int s = 0; s < 5; ++s) {
    const int jx = w0 + s;
    const float g = __expf(cd[s] * INV_T);
    if (jx == i) {
      num += g;  // strong term
    } else {
      const float d = (float)(jx - i);
      const float pw = __expf(-d * d * 0.125f);
      const float ratio = sqrtf(r[(size_t)b * NN_ + jx]) * rsi;  // sqrt(r_j / r_i)
      const float mband = b2f(M[(size_t)i * NN_ + jx]);
      const float m2band = b2f(M2[(size_t)i * NN_ + jx]);
      const float sc = 0.5f * pw + ratio * (mband + m2band + a4[s]) * (0.5f / 3.0f);
      num += sc * g;
    }
  }

  if (lane == 0) {
    const float dn = den[(size_t)b * NN_ + i];                     // read own slot...
    den[(size_t)b * NN_ + i] = -logf(num / (dn + 1e-9f) + 1e-9f);  // ...then overwrite with loss
  }
}

// ---------------- final mean over den1||den2 (2*BB*NN_ floats, contiguous) ----------------
__global__ __launch_bounds__(256) void k_final(const float* __restrict__ lossRows, float* __restrict__ out) {
  const int t = threadIdx.x;
  float s = 0.f;
  for (int idx = t; idx < BB * 2 * NN_; idx += 256) s += lossRows[idx];
#pragma unroll
  for (int o = 32; o; o >>= 1) s += __shfl_xor(s, o);
  __shared__ float p[4];
  if ((t & 63) == 0) p[t >> 6] = s;
  __syncthreads();
  if (t == 0) out[0] = (p[0] + p[1] + p[2] + p[3]) / (float)(BB * 2 * NN_);
}

extern "C" void kernel_launch(void* const* d_in, const int* in_sizes, int n_in, void* d_out, int out_size,
                              void* d_ws, size_t ws_size, hipStream_t stream) {
  const float* z1 = (const float*)d_in[0];
  const float* z2 = (const float*)d_in[1];
  float* out = (float*)d_out;

  const size_t nzd = (size_t)BB * NN_ * DD;
  const size_t nnn = (size_t)BB * NN_ * NN_;
  const size_t nv = (size_t)BB * NN_;

  ushort* znAll = (ushort*)d_ws;                // 2*nzd
  ushort* XY = znAll + 2 * nzd;                 // X (h2 M) then Y (h1 M): 2*nnn
  ushort* ZW = XY + 2 * nnn;                    // Z (h2 M^2) then W (h1 M^2): 2*nnn
  float* den1 = (float*)(ZW + 2 * nnn);         // den1, den2, rsum1, rsum2: 4*nv
  float* den2 = den1 + nv;
  float* rsum1 = den2 + nv;
  float* rsum2 = rsum1 + nv;

  const size_t needed = 2 * nzd * 2 + 4 * nnn * 2 + 4 * nv * 4;  // 151,257,088 B (proven available)
  if (ws_size < needed) return;  // fail cleanly instead of faulting

  dim3 blk(256);

  // 1) norm (wave-per-row) + zero vectors
  k_norm<<<(2 * BB * NN_) / 4, blk, 0, stream>>>(z1, z2, znAll, den1);

  // 2) SIM_SAME(h2 -> X) + SIM_SAME(h1 -> Y) + CROSS, one launch
  k_mega256<<<1152 + 1024, blk, 0, stream>>>(znAll, XY, den1, den2, rsum1, rsum2);

  // 3) scale both halves in place: X,Y -> M(h2), M(h1)
  k_scale<<<(int)(2 * nnn / 2048), blk, 0, stream>>>(XY, rsum1, rsum2);

  // 4) Z = M(h2)^2, W = M(h1)^2, one launch (TRI + mirror)
  k_megasq<<<1152, blk, 0, stream>>>(XY, ZW);

  // 5) both loss halves (XCD-swizzled); loss written into den slots
  k_megaloss<<<(int)(2 * nv / 4), blk, 0, stream>>>(XY, ZW, znAll, rsum1, rsum2, den1, den2);

  // 6) mean over den1||den2
  k_final<<<1, blk, 0, stream>>>(den1, out);
}